// Round 14
// baseline (287.816 us; speedup 1.0000x reference)
//
#include <hip/hip_runtime.h>
#include <stdint.h>

#define TT 4096
#define HIDD 1024

typedef __attribute__((ext_vector_type(4))) float f32x4;
typedef __attribute__((ext_vector_type(8))) short s16x8;

static constexpr float kEps = 1e-6f;
static constexpr float kCsc = 0.125f * 1.44269504088896f;  // scale * log2(e), folded into q

// ---- workspace layout (bytes); lifetimes ----
static constexpr size_t OFF_HS   = 0;          // bf16 hs swz [4096][1024] 8 MB   (dies after gemm_qkv)
static constexpr size_t OFF_WQKV = 8388608;    // bf16 WqkvT  [1536][1024] 3 MB   (dies after gemm_qkv)
static constexpr size_t OFF_OBUF = 0;          // f32 O partial [4096][1024] 16.78 MB (overlays hs+wqkv)
static constexpr size_t OFF_LBUF = 16777216;   // f32 l partial [16][4096] 256 KB
static constexpr size_t OFF_WO   = 17039360;   // bf16 WoT [1024][1024] 2 MB
static constexpr size_t OFF_Q    = 19136512;   // bf16 q [16][4096][64] 8 MB
static constexpr size_t OFF_K    = 27525120;   // bf16 k swz [4][4096][64] 2 MB
static constexpr size_t OFF_VT   = 29622272;   // bf16 vT swz [4][64][4096] 2 MB
static constexpr size_t OFF_O    = 31719424;   // bf16 attn-out swz [4096][1024] 8 MB

__device__ __forceinline__ unsigned int pk_bf16(float a, float b) {
  union { float f; unsigned int u; } x, y;
  x.f = a; y.f = b;
  unsigned int lo = (x.u + 0x7fffu + ((x.u >> 16) & 1u)) >> 16;
  unsigned int hi = (y.u + 0x7fffu + ((y.u >> 16) & 1u)) >> 16;
  return (lo & 0xffffu) | (hi << 16);
}
__device__ __forceinline__ unsigned int cvtpk(float lo, float hi) {
  unsigned int r;
  asm("v_cvt_pk_bf16_f32 %0, %1, %2" : "=v"(r) : "v"(lo), "v"(hi));
  return r;
}
__device__ __forceinline__ void gload16(const void* g, void* l) {
  __builtin_amdgcn_global_load_lds(
      (const __attribute__((address_space(1))) unsigned int*)g,
      (__attribute__((address_space(3))) unsigned int*)l, 16, 0, 0);
}

// hs fp32 [T][1024] -> bf16 swizzled
__global__ void k_convert_hs(const float* __restrict__ hs, unsigned short* __restrict__ out) {
  int idx = blockIdx.x * 256 + threadIdx.x;  // T*128
  int t = idx >> 7, kc = idx & 127;
  const float4* src = (const float4*)(hs + (size_t)t * HIDD + kc * 8);
  float4 a = src[0], b = src[1];
  int kcs = (kc & ~7) | ((kc & 7) ^ (t & 7));
  uint4 w;
  w.x = pk_bf16(a.x, a.y); w.y = pk_bf16(a.z, a.w);
  w.z = pk_bf16(b.x, b.y); w.w = pk_bf16(b.z, b.w);
  *(uint4*)(out + (size_t)t * HIDD + kcs * 8) = w;
}

// All four weight matrices: fp32 [1024][ncols] -> bf16 W^T [ncols][1024] swizzled by n&7
__global__ void k_convert_w_all(const float* __restrict__ Wq, const float* __restrict__ Wk,
                                const float* __restrict__ Wv, const float* __restrict__ Wo,
                                unsigned short* __restrict__ wqkv, unsigned short* __restrict__ wo_t) {
  int b = blockIdx.x, tid = threadIdx.x;
  const float* W; unsigned short* outT; int nshift, idx;
  if (b < 512)      { W = Wq; outT = wqkv;                nshift = 10; idx = b * 256 + tid; }
  else if (b < 640) { W = Wk; outT = wqkv + 1024 * 1024;  nshift = 8;  idx = (b - 512) * 256 + tid; }
  else if (b < 768) { W = Wv; outT = wqkv + 1280 * 1024;  nshift = 8;  idx = (b - 640) * 256 + tid; }
  else              { W = Wo; outT = wo_t;                nshift = 10; idx = (b - 768) * 256 + tid; }
  int ncols = 1 << nshift;
  int kc = idx >> nshift, n = idx & (ncols - 1);
  float v[8];
#pragma unroll
  for (int e = 0; e < 8; ++e) v[e] = W[(size_t)(kc * 8 + e) * ncols + n];
  int kcs = (kc & ~7) | ((kc & 7) ^ (n & 7));
  uint4 w;
  w.x = pk_bf16(v[0], v[1]); w.y = pk_bf16(v[2], v[3]);
  w.z = pk_bf16(v[4], v[5]); w.w = pk_bf16(v[6], v[7]);
  *(uint4*)(outT + (size_t)n * HIDD + kcs * 8) = w;
}

// Fused QKV GEMM + RMSNorm + RoPE + bf16 layout conversion (R12, verified).
__global__ __launch_bounds__(256) void k_gemm_qkv(const unsigned short* __restrict__ A,
                                                  const unsigned short* __restrict__ Bt,
                                                  const float* __restrict__ cosb,
                                                  const float* __restrict__ sinb,
                                                  const float* __restrict__ qw,
                                                  const float* __restrict__ kw,
                                                  unsigned short* __restrict__ qo,
                                                  unsigned short* __restrict__ ko,
                                                  unsigned short* __restrict__ vt) {
  __shared__ __attribute__((aligned(16))) char smem[49152];
  const int K = HIDD;
  const int tid = threadIdx.x;
  const int m0 = blockIdx.y * 128, slot = blockIdx.x, n0 = slot * 64;
  const int wid = tid >> 6, lane = tid & 63;
  const int g = lane >> 4, qi = lane & 15;
  const int wr = wid >> 1, wc = wid & 1;
  const int srow = lane >> 3, schk = lane & 7;
  f32x4 acc[4][2] = {};
  const int nkt = K >> 6;

  auto STAGE = [&](int b, int k0) {
#pragma unroll
    for (int j = 0; j < 4; ++j) {
      int ra = j * 32 + wid * 8 + srow;
      gload16(A + (size_t)(m0 + ra) * K + k0 + schk * 8,
              smem + b * 16384 + j * 4096 + (wid << 10));
    }
#pragma unroll
    for (int j = 0; j < 2; ++j) {
      int rb = j * 32 + wid * 8 + srow;
      gload16(Bt + (size_t)(n0 + rb) * K + k0 + schk * 8,
              smem + 32768 + b * 8192 + j * 4096 + (wid << 10));
    }
  };

  STAGE(0, 0);
  __syncthreads();
  int cur = 0;
  for (int kt = 0; kt < nkt; ++kt) {
    if (kt + 1 < nkt) STAGE(cur ^ 1, (kt + 1) << 6);
#pragma unroll
    for (int kh = 0; kh < 2; ++kh) {
      s16x8 af[4], bq[2];
#pragma unroll
      for (int i = 0; i < 4; ++i) {
        int rA = wr * 64 + i * 16 + qi;
        af[i] = *(const s16x8*)(smem + cur * 16384 + rA * 128 + ((((kh << 2) | g) ^ (rA & 7)) << 4));
      }
#pragma unroll
      for (int jn = 0; jn < 2; ++jn) {
        int rB = wc * 32 + jn * 16 + qi;
        bq[jn] = *(const s16x8*)(smem + 32768 + cur * 8192 + rB * 128 + ((((kh << 2) | g) ^ (rB & 7)) << 4));
      }
      __builtin_amdgcn_s_setprio(1);
#pragma unroll
      for (int i = 0; i < 4; ++i)
#pragma unroll
        for (int jn = 0; jn < 2; ++jn)
          acc[i][jn] = __builtin_amdgcn_mfma_f32_16x16x32_bf16(af[i], bq[jn], acc[i][jn], 0, 0, 0);
      __builtin_amdgcn_s_setprio(0);
    }
    __syncthreads();
    cur ^= 1;
  }

  // ---- epilogue ----
  float* Cs = (float*)smem;                 // [128][66] f32
#pragma unroll
  for (int i = 0; i < 4; ++i)
#pragma unroll
    for (int jn = 0; jn < 2; ++jn) {
      int row = wr * 64 + i * 16 + g * 4;
      int col = wc * 32 + jn * 16 + qi;
#pragma unroll
      for (int r = 0; r < 4; ++r)
        Cs[(row + r) * 66 + col] = acc[i][jn][r];
    }
  __syncthreads();

  if (slot < 20) {
    const int lr = tid >> 1, hf = tid & 1;
    const int t = m0 + lr;
    const float* self_p = Cs + lr * 66 + hf * 32;
    const float* oth_p  = Cs + lr * 66 + (1 - hf) * 32;
    float ss = 0.0f;
#pragma unroll
    for (int e = 0; e < 32; ++e) { float v = self_p[e]; ss += v * v; }
    ss += __shfl_xor(ss, 1);
    const float rms = rsqrtf(ss * (1.0f / 64.0f) + kEps);
    const float* wvec = (slot < 16) ? qw : kw;
    const float outscale = (slot < 16) ? kCsc : 1.0f;
    unsigned int u[16];
#pragma unroll
    for (int ee = 0; ee < 16; ++ee) {
      float o2[2];
#pragma unroll
      for (int p = 0; p < 2; ++p) {
        int e = 2 * ee + p;
        float c = cosb[t * 32 + e];
        float s = sinb[t * 32 + e];
        float self = self_p[e] * rms * wvec[hf * 32 + e];
        float oth  = oth_p[e]  * rms * wvec[(1 - hf) * 32 + e];
        float r = hf ? (oth * s + self * c) : (self * c - oth * s);
        o2[p] = r * outscale;
      }
      u[ee] = cvtpk(o2[0], o2[1]);
    }
    if (slot < 16) {
      unsigned short* base = qo + ((size_t)slot * TT + t) * 64 + hf * 32;
#pragma unroll
      for (int cidx = 0; cidx < 4; ++cidx) {
        uint4 w; w.x = u[cidx * 4]; w.y = u[cidx * 4 + 1]; w.z = u[cidx * 4 + 2]; w.w = u[cidx * 4 + 3];
        *(uint4*)(base + cidx * 8) = w;
      }
    } else {
      const int hv = slot - 16;
      unsigned short* base = ko + ((size_t)hv * TT + t) * 64;
#pragma unroll
      for (int cidx = 0; cidx < 4; ++cidx) {
        int gc = hf * 4 + cidx;
        uint4 w; w.x = u[cidx * 4]; w.y = u[cidx * 4 + 1]; w.z = u[cidx * 4 + 2]; w.w = u[cidx * 4 + 3];
        *(uint4*)(base + (gc ^ (t & 7)) * 8) = w;
      }
    }
  } else {
    const int hv = slot - 20;
#pragma unroll
    for (int tt = 0; tt < 2; ++tt)
#pragma unroll
      for (int jj = 0; jj < 2; ++jj) {
        int idx = jj * 256 + tid;
        int d = idx >> 3, tc = idx & 7;
        uint4 w;
        w.x = cvtpk(Cs[(tt * 64 + tc * 8 + 0) * 66 + d], Cs[(tt * 64 + tc * 8 + 1) * 66 + d]);
        w.y = cvtpk(Cs[(tt * 64 + tc * 8 + 2) * 66 + d], Cs[(tt * 64 + tc * 8 + 3) * 66 + d]);
        w.z = cvtpk(Cs[(tt * 64 + tc * 8 + 4) * 66 + d], Cs[(tt * 64 + tc * 8 + 5) * 66 + d]);
        w.w = cvtpk(Cs[(tt * 64 + tc * 8 + 6) * 66 + d], Cs[(tt * 64 + tc * 8 + 7) * 66 + d]);
        int tcs = tc ^ (d & 7);
        *(uint4*)(vt + ((size_t)hv * 64 + d) * TT + m0 + tt * 64 + tcs * 8) = w;
      }
  }
}

// C[M][N] = A[M][K] * Bt[N][K]^T ; 128x64 tile, BK=64, 4 waves, dbuf LDS (output proj).
__global__ __launch_bounds__(256) void k_gemm(const unsigned short* __restrict__ A,
                                              const unsigned short* __restrict__ Bt,
                                              float* __restrict__ C, int M, int N, int K) {
  __shared__ __attribute__((aligned(16))) unsigned short As[2][128 * 64];
  __shared__ __attribute__((aligned(16))) unsigned short Bs[2][64 * 64];
  const int tid = threadIdx.x;
  const int m0 = blockIdx.y * 128, n0 = blockIdx.x * 64;
  const int wid = tid >> 6, lane = tid & 63;
  const int g = lane >> 4, qi = lane & 15;
  const int wr = wid >> 1, wc = wid & 1;
  const int srow = lane >> 3, schk = lane & 7;
  f32x4 acc[4][2] = {};
  const int nkt = K >> 6;

  auto STAGE = [&](int b, int k0) {
#pragma unroll
    for (int j = 0; j < 4; ++j) {
      int ra = j * 32 + wid * 8 + srow;
      gload16(A + (size_t)(m0 + ra) * K + k0 + schk * 8,
              (char*)&As[b][0] + j * 4096 + (wid << 10));
    }
#pragma unroll
    for (int j = 0; j < 2; ++j) {
      int rb = j * 32 + wid * 8 + srow;
      gload16(Bt + (size_t)(n0 + rb) * K + k0 + schk * 8,
              (char*)&Bs[b][0] + j * 4096 + (wid << 10));
    }
  };

  STAGE(0, 0);
  __syncthreads();
  int cur = 0;
  for (int kt = 0; kt < nkt; ++kt) {
    if (kt + 1 < nkt) STAGE(cur ^ 1, (kt + 1) << 6);
#pragma unroll
    for (int kh = 0; kh < 2; ++kh) {
      s16x8 af[4], bq[2];
#pragma unroll
      for (int i = 0; i < 4; ++i) {
        int rA = wr * 64 + i * 16 + qi;
        af[i] = *(const s16x8*)((const char*)&As[cur][0] + rA * 128 + ((((kh << 2) | g) ^ (rA & 7)) << 4));
      }
#pragma unroll
      for (int jn = 0; jn < 2; ++jn) {
        int rB = wc * 32 + jn * 16 + qi;
        bq[jn] = *(const s16x8*)((const char*)&Bs[cur][0] + rB * 128 + ((((kh << 2) | g) ^ (rB & 7)) << 4));
      }
      __builtin_amdgcn_s_setprio(1);
#pragma unroll
      for (int i = 0; i < 4; ++i)
#pragma unroll
        for (int jn = 0; jn < 2; ++jn)
          acc[i][jn] = __builtin_amdgcn_mfma_f32_16x16x32_bf16(af[i], bq[jn], acc[i][jn], 0, 0, 0);
      __builtin_amdgcn_s_setprio(0);
    }
    __syncthreads();
    cur ^= 1;
  }
#pragma unroll
  for (int i = 0; i < 4; ++i)
#pragma unroll
    for (int jn = 0; jn < 2; ++jn) {
      int row = m0 + wr * 64 + i * 16 + g * 4;
      int col = n0 + wc * 32 + jn * 16 + qi;
#pragma unroll
      for (int r = 0; r < 4; ++r)
        C[(size_t)(row + r) * N + col] = acc[i][jn][r];
    }
}

// Flash attention, causal GQA — R5's proven 8-wave x 16q inner loop, but work unit =
// (head, 128-row band, kv-HALF): 1024 independent uniform-structure blocks (len band+1),
// longest-first within each XCD, 40960B LDS -> exactly 4 blocks/CU (vs 512-block/2-CU pin).
// Fixed-max softmax makes kv-halves independent; O/l merged via f32 atomicAdd (exactly 2
// deterministic contributions per address, R13-verified). P buffer written per-kh (1KB/wave).
__global__ __launch_bounds__(512, 8) void k_attn(const unsigned short* __restrict__ q,
                                                 const unsigned short* __restrict__ kk,
                                                 const unsigned short* __restrict__ vt,
                                                 float* __restrict__ obuf,
                                                 float* __restrict__ lbuf) {
  __shared__ __attribute__((aligned(16))) char smem[40960];  // K dbuf 16K @0, V dbuf 16K @16384, P 8K @32768
  const int tid = threadIdx.x;
  const int wid = tid >> 6, lane = tid & 63, g = lane >> 4, qi = lane & 15;
  const int bid = blockIdx.x;
  const int xcd = bid & 7;
  const int rem = bid >> 3;                  // [0,128) per XCD
  const int b_ord = rem >> 2, sub = rem & 3;
  const int head = xcd * 2 + (sub >> 1);     // 2 heads per XCD (KV L2-resident)
  const int half = sub & 1;
  const int band = 31 - b_ord;               // longest-first
  const int len = band + 1;
  const int kvlo = half * len;
  const int hv = head >> 2;
  char* pb = smem + 32768 + (wid << 10);

  auto STAGE = [&](int b, int kvt) {
    const int row = tid >> 3, ch = tid & 7;
    gload16(kk + ((size_t)hv * TT + kvt * 64 + row) * 64 + ch * 8,
            smem + b * 8192 + tid * 16);
    gload16(vt + ((size_t)hv * 64 + row) * TT + kvt * 64 + ch * 8,
            smem + 16384 + b * 8192 + tid * 16);
  };

  const int qg = band * 128 + wid * 16 + qi;
  const int diagT = 2 * band + (wid >> 2);
  s16x8 qf[2];
#pragma unroll
  for (int kh = 0; kh < 2; ++kh)
    qf[kh] = *(const s16x8*)(q + ((size_t)head * TT + qg) * 64 + kh * 32 + g * 8);
  f32x4 acc[4] = {};
  float l0 = 0.0f, l1 = 0.0f;

  STAGE(0, kvlo);
  __syncthreads();
  int cur = 0;
  for (int ss = 0; ss < len; ++ss) {
    if (ss + 1 < len) STAGE(cur ^ 1, kvlo + ss + 1);
    const int kvt = kvlo + ss;
    if (kvt <= diagT) {
      const int kv0 = kvt * 64;
      const char* Kb = smem + cur * 8192;
      const char* Vb = smem + 16384 + cur * 8192;
      f32x4 sacc[4] = {};
#pragma unroll
      for (int kh = 0; kh < 2; ++kh) {
        s16x8 kf[4];
#pragma unroll
        for (int cf = 0; cf < 4; ++cf) {
          int row = cf * 16 + qi;
          kf[cf] = *(const s16x8*)(Kb + row * 128 + ((((kh << 2) | g) ^ (row & 7)) << 4));
        }
        __builtin_amdgcn_s_setprio(1);
#pragma unroll
        for (int cf = 0; cf < 4; ++cf)
          sacc[cf] = __builtin_amdgcn_mfma_f32_16x16x32_bf16(kf[cf], qf[kh], sacc[cf], 0, 0, 0);
        __builtin_amdgcn_s_setprio(0);
      }
      float pv[16];
      if (kvt == diagT) {
#pragma unroll
        for (int cf = 0; cf < 4; ++cf)
#pragma unroll
          for (int r = 0; r < 4; ++r) {
            float v = sacc[cf][r];
            if ((kv0 + cf * 16 + g * 4 + r) > qg) v = -1e30f;
            pv[cf * 4 + r] = v;
          }
      } else {
#pragma unroll
        for (int cf = 0; cf < 4; ++cf)
#pragma unroll
          for (int r = 0; r < 4; ++r) pv[cf * 4 + r] = sacc[cf][r];
      }
#pragma unroll
      for (int i = 0; i < 8; ++i) {
        float e0 = exp2f(pv[2 * i]), e1 = exp2f(pv[2 * i + 1]);
        pv[2 * i] = e0; pv[2 * i + 1] = e1;
        l0 += e0; l1 += e1;
      }
      // per-kh: write P half (16q x 32kv, 1KB), read pf, PV MFMA
#pragma unroll
      for (int kh = 0; kh < 2; ++kh) {
#pragma unroll
        for (int cl = 0; cl < 2; ++cl) {
          int cf = 2 * kh + cl;
          uint2 pw;
          pw.x = cvtpk(pv[cf * 4 + 0], pv[cf * 4 + 1]);
          pw.y = cvtpk(pv[cf * 4 + 2], pv[cf * 4 + 3]);
          *(uint2*)(pb + qi * 64 + cl * 32 + g * 8) = pw;
        }
        s16x8 pf = *(const s16x8*)(pb + qi * 64 + g * 16);
        s16x8 vf[4];
#pragma unroll
        for (int cf = 0; cf < 4; ++cf) {
          int row = cf * 16 + qi;
          vf[cf] = *(const s16x8*)(Vb + row * 128 + ((((kh << 2) | g) ^ (row & 7)) << 4));
        }
        __builtin_amdgcn_s_setprio(1);
#pragma unroll
        for (int cf = 0; cf < 4; ++cf)
          acc[cf] = __builtin_amdgcn_mfma_f32_16x16x32_bf16(vf[cf], pf, acc[cf], 0, 0, 0);
        __builtin_amdgcn_s_setprio(0);
      }
    }
    __syncthreads();
    cur ^= 1;
  }
  // flush unnormalized partials (2 contributions per address: the two kv-halves)
  float l_run = l0 + l1;
  l_run += __shfl_xor(l_run, 16);
  l_run += __shfl_xor(l_run, 32);
  if (lane < 16)
    unsafeAtomicAdd(lbuf + (size_t)head * TT + band * 128 + wid * 16 + qi, l_run);
#pragma unroll
  for (int cf = 0; cf < 4; ++cf)
#pragma unroll
    for (int r = 0; r < 4; ++r)
      unsafeAtomicAdd(obuf + (size_t)qg * 1024 + head * 64 + cf * 16 + g * 4 + r, acc[cf][r]);
}

// O = obuf / l, packed to bf16 obf (chunk-swizzled [t][1024], gemm2 A layout)
__global__ void k_norm(const float* __restrict__ obuf, const float* __restrict__ lbuf,
                       unsigned short* __restrict__ obf) {
  int idx = blockIdx.x * 256 + threadIdx.x;   // T*128
  int t = idx >> 7, kc = idx & 127;
  const float4* src = (const float4*)(obuf + (size_t)t * 1024 + kc * 8);
  float inv = 1.0f / lbuf[(size_t)(kc >> 3) * TT + t];
  float4 a = src[0], b = src[1];
  uint4 w;
  w.x = cvtpk(a.x * inv, a.y * inv); w.y = cvtpk(a.z * inv, a.w * inv);
  w.z = cvtpk(b.x * inv, b.y * inv); w.w = cvtpk(b.z * inv, b.w * inv);
  int kcs = (kc & ~7) | ((kc & 7) ^ (t & 7));
  *(uint4*)(obf + (size_t)t * 1024 + kcs * 8) = w;
}

extern "C" void kernel_launch(void* const* d_in, const int* in_sizes, int n_in,
                              void* d_out, int out_size, void* d_ws, size_t ws_size,
                              hipStream_t stream) {
  const float* hs   = (const float*)d_in[0];
  const float* cosb = (const float*)d_in[1];
  const float* sinb = (const float*)d_in[2];
  const float* Wq   = (const float*)d_in[3];
  const float* Wk   = (const float*)d_in[4];
  const float* Wv   = (const float*)d_in[5];
  const float* Wo   = (const float*)d_in[6];
  const float* qw   = (const float*)d_in[7];
  const float* kw   = (const float*)d_in[8];
  char* ws = (char*)d_ws;
  unsigned short* hs_swz = (unsigned short*)(ws + OFF_HS);
  unsigned short* wqkv   = (unsigned short*)(ws + OFF_WQKV);
  float*          obuf   = (float*)(ws + OFF_OBUF);
  float*          lbuf   = (float*)(ws + OFF_LBUF);
  unsigned short* wo_t   = (unsigned short*)(ws + OFF_WO);
  unsigned short* qbf    = (unsigned short*)(ws + OFF_Q);
  unsigned short* kbf    = (unsigned short*)(ws + OFF_K);
  unsigned short* vtb    = (unsigned short*)(ws + OFF_VT);
  unsigned short* obf    = (unsigned short*)(ws + OFF_O);

  k_convert_hs<<<2048, 256, 0, stream>>>(hs, hs_swz);
  k_convert_w_all<<<1280, 256, 0, stream>>>(Wq, Wk, Wv, Wo, wqkv, wo_t);
  k_gemm_qkv<<<dim3(24, 32), 256, 0, stream>>>(hs_swz, wqkv, cosb, sinb, qw, kw, qbf, kbf, vtb);
  hipMemsetAsync(obuf, 0, (size_t)4096 * 1024 * 4, stream);   // overlays dead hs_swz/wqkv
  hipMemsetAsync(lbuf, 0, (size_t)16 * 4096 * 4, stream);
  k_attn<<<1024, 512, 0, stream>>>(qbf, kbf, vtb, obuf, lbuf);
  k_norm<<<2048, 256, 0, stream>>>(obuf, lbuf, obf);
  k_gemm<<<dim3(16, 32), 256, 0, stream>>>(obf, wo_t, (float*)d_out, 4096, 1024, 1024);
}

// Round 15
// 219.159 us; speedup vs baseline: 1.3133x; 1.3133x over previous
//
#include <hip/hip_runtime.h>
#include <stdint.h>

#define TT 4096
#define HIDD 1024

typedef __attribute__((ext_vector_type(4))) float f32x4;
typedef __attribute__((ext_vector_type(8))) short s16x8;

static constexpr float kEps = 1e-6f;
static constexpr float kCsc = 0.125f * 1.44269504088896f;  // scale * log2(e), folded into q

// ---- workspace layout (bytes); lifetimes ----
static constexpr size_t OFF_HS   = 0;          // bf16 hs swz [4096][1024] 8 MB   (dies after gemm_qkv)
static constexpr size_t OFF_WQKV = 8388608;    // bf16 WqkvT  [1536][1024] 3 MB   (dies after gemm_qkv)
static constexpr size_t OFF_OBUF = 0;          // f32 O partial [4096][1024] 16.78 MB (overlays hs+wqkv)
static constexpr size_t OFF_LBUF = 16777216;   // f32 l partial [16][4096] 256 KB
static constexpr size_t OFF_WO   = 17039360;   // bf16 WoT [1024][1024] 2 MB
static constexpr size_t OFF_Q    = 19136512;   // bf16 q [16][4096][64] 8 MB
static constexpr size_t OFF_K    = 27525120;   // bf16 k swz [4][4096][64] 2 MB
static constexpr size_t OFF_VT   = 29622272;   // bf16 vT swz [4][64][4096] 2 MB
static constexpr size_t OFF_O    = 31719424;   // bf16 attn-out swz [4096][1024] 8 MB

__device__ __forceinline__ unsigned int pk_bf16(float a, float b) {
  union { float f; unsigned int u; } x, y;
  x.f = a; y.f = b;
  unsigned int lo = (x.u + 0x7fffu + ((x.u >> 16) & 1u)) >> 16;
  unsigned int hi = (y.u + 0x7fffu + ((y.u >> 16) & 1u)) >> 16;
  return (lo & 0xffffu) | (hi << 16);
}
__device__ __forceinline__ unsigned int cvtpk(float lo, float hi) {
  unsigned int r;
  asm("v_cvt_pk_bf16_f32 %0, %1, %2" : "=v"(r) : "v"(lo), "v"(hi));
  return r;
}
__device__ __forceinline__ void gload16(const void* g, void* l) {
  __builtin_amdgcn_global_load_lds(
      (const __attribute__((address_space(1))) unsigned int*)g,
      (__attribute__((address_space(3))) unsigned int*)l, 16, 0, 0);
}

// hs fp32 [T][1024] -> bf16 swizzled
__global__ void k_convert_hs(const float* __restrict__ hs, unsigned short* __restrict__ out) {
  int idx = blockIdx.x * 256 + threadIdx.x;  // T*128
  int t = idx >> 7, kc = idx & 127;
  const float4* src = (const float4*)(hs + (size_t)t * HIDD + kc * 8);
  float4 a = src[0], b = src[1];
  int kcs = (kc & ~7) | ((kc & 7) ^ (t & 7));
  uint4 w;
  w.x = pk_bf16(a.x, a.y); w.y = pk_bf16(a.z, a.w);
  w.z = pk_bf16(b.x, b.y); w.w = pk_bf16(b.z, b.w);
  *(uint4*)(out + (size_t)t * HIDD + kcs * 8) = w;
}

// All four weight matrices: fp32 [1024][ncols] -> bf16 W^T [ncols][1024] swizzled by n&7
__global__ void k_convert_w_all(const float* __restrict__ Wq, const float* __restrict__ Wk,
                                const float* __restrict__ Wv, const float* __restrict__ Wo,
                                unsigned short* __restrict__ wqkv, unsigned short* __restrict__ wo_t) {
  int b = blockIdx.x, tid = threadIdx.x;
  const float* W; unsigned short* outT; int nshift, idx;
  if (b < 512)      { W = Wq; outT = wqkv;                nshift = 10; idx = b * 256 + tid; }
  else if (b < 640) { W = Wk; outT = wqkv + 1024 * 1024;  nshift = 8;  idx = (b - 512) * 256 + tid; }
  else if (b < 768) { W = Wv; outT = wqkv + 1280 * 1024;  nshift = 8;  idx = (b - 640) * 256 + tid; }
  else              { W = Wo; outT = wo_t;                nshift = 10; idx = (b - 768) * 256 + tid; }
  int ncols = 1 << nshift;
  int kc = idx >> nshift, n = idx & (ncols - 1);
  float v[8];
#pragma unroll
  for (int e = 0; e < 8; ++e) v[e] = W[(size_t)(kc * 8 + e) * ncols + n];
  int kcs = (kc & ~7) | ((kc & 7) ^ (n & 7));
  uint4 w;
  w.x = pk_bf16(v[0], v[1]); w.y = pk_bf16(v[2], v[3]);
  w.z = pk_bf16(v[4], v[5]); w.w = pk_bf16(v[6], v[7]);
  *(uint4*)(outT + (size_t)n * HIDD + kcs * 8) = w;
}

// Fused QKV GEMM + RMSNorm + RoPE + bf16 layout conversion (R12, verified).
__global__ __launch_bounds__(256) void k_gemm_qkv(const unsigned short* __restrict__ A,
                                                  const unsigned short* __restrict__ Bt,
                                                  const float* __restrict__ cosb,
                                                  const float* __restrict__ sinb,
                                                  const float* __restrict__ qw,
                                                  const float* __restrict__ kw,
                                                  unsigned short* __restrict__ qo,
                                                  unsigned short* __restrict__ ko,
                                                  unsigned short* __restrict__ vt) {
  __shared__ __attribute__((aligned(16))) char smem[49152];
  const int K = HIDD;
  const int tid = threadIdx.x;
  const int m0 = blockIdx.y * 128, slot = blockIdx.x, n0 = slot * 64;
  const int wid = tid >> 6, lane = tid & 63;
  const int g = lane >> 4, qi = lane & 15;
  const int wr = wid >> 1, wc = wid & 1;
  const int srow = lane >> 3, schk = lane & 7;
  f32x4 acc[4][2] = {};
  const int nkt = K >> 6;

  auto STAGE = [&](int b, int k0) {
#pragma unroll
    for (int j = 0; j < 4; ++j) {
      int ra = j * 32 + wid * 8 + srow;
      gload16(A + (size_t)(m0 + ra) * K + k0 + schk * 8,
              smem + b * 16384 + j * 4096 + (wid << 10));
    }
#pragma unroll
    for (int j = 0; j < 2; ++j) {
      int rb = j * 32 + wid * 8 + srow;
      gload16(Bt + (size_t)(n0 + rb) * K + k0 + schk * 8,
              smem + 32768 + b * 8192 + j * 4096 + (wid << 10));
    }
  };

  STAGE(0, 0);
  __syncthreads();
  int cur = 0;
  for (int kt = 0; kt < nkt; ++kt) {
    if (kt + 1 < nkt) STAGE(cur ^ 1, (kt + 1) << 6);
#pragma unroll
    for (int kh = 0; kh < 2; ++kh) {
      s16x8 af[4], bq[2];
#pragma unroll
      for (int i = 0; i < 4; ++i) {
        int rA = wr * 64 + i * 16 + qi;
        af[i] = *(const s16x8*)(smem + cur * 16384 + rA * 128 + ((((kh << 2) | g) ^ (rA & 7)) << 4));
      }
#pragma unroll
      for (int jn = 0; jn < 2; ++jn) {
        int rB = wc * 32 + jn * 16 + qi;
        bq[jn] = *(const s16x8*)(smem + 32768 + cur * 8192 + rB * 128 + ((((kh << 2) | g) ^ (rB & 7)) << 4));
      }
      __builtin_amdgcn_s_setprio(1);
#pragma unroll
      for (int i = 0; i < 4; ++i)
#pragma unroll
        for (int jn = 0; jn < 2; ++jn)
          acc[i][jn] = __builtin_amdgcn_mfma_f32_16x16x32_bf16(af[i], bq[jn], acc[i][jn], 0, 0, 0);
      __builtin_amdgcn_s_setprio(0);
    }
    __syncthreads();
    cur ^= 1;
  }

  // ---- epilogue ----
  float* Cs = (float*)smem;                 // [128][66] f32
#pragma unroll
  for (int i = 0; i < 4; ++i)
#pragma unroll
    for (int jn = 0; jn < 2; ++jn) {
      int row = wr * 64 + i * 16 + g * 4;
      int col = wc * 32 + jn * 16 + qi;
#pragma unroll
      for (int r = 0; r < 4; ++r)
        Cs[(row + r) * 66 + col] = acc[i][jn][r];
    }
  __syncthreads();

  if (slot < 20) {
    const int lr = tid >> 1, hf = tid & 1;
    const int t = m0 + lr;
    const float* self_p = Cs + lr * 66 + hf * 32;
    const float* oth_p  = Cs + lr * 66 + (1 - hf) * 32;
    float ss = 0.0f;
#pragma unroll
    for (int e = 0; e < 32; ++e) { float v = self_p[e]; ss += v * v; }
    ss += __shfl_xor(ss, 1);
    const float rms = rsqrtf(ss * (1.0f / 64.0f) + kEps);
    const float* wvec = (slot < 16) ? qw : kw;
    const float outscale = (slot < 16) ? kCsc : 1.0f;
    unsigned int u[16];
#pragma unroll
    for (int ee = 0; ee < 16; ++ee) {
      float o2[2];
#pragma unroll
      for (int p = 0; p < 2; ++p) {
        int e = 2 * ee + p;
        float c = cosb[t * 32 + e];
        float s = sinb[t * 32 + e];
        float self = self_p[e] * rms * wvec[hf * 32 + e];
        float oth  = oth_p[e]  * rms * wvec[(1 - hf) * 32 + e];
        float r = hf ? (oth * s + self * c) : (self * c - oth * s);
        o2[p] = r * outscale;
      }
      u[ee] = cvtpk(o2[0], o2[1]);
    }
    if (slot < 16) {
      unsigned short* base = qo + ((size_t)slot * TT + t) * 64 + hf * 32;
#pragma unroll
      for (int cidx = 0; cidx < 4; ++cidx) {
        uint4 w; w.x = u[cidx * 4]; w.y = u[cidx * 4 + 1]; w.z = u[cidx * 4 + 2]; w.w = u[cidx * 4 + 3];
        *(uint4*)(base + cidx * 8) = w;
      }
    } else {
      const int hv = slot - 16;
      unsigned short* base = ko + ((size_t)hv * TT + t) * 64;
#pragma unroll
      for (int cidx = 0; cidx < 4; ++cidx) {
        int gc = hf * 4 + cidx;
        uint4 w; w.x = u[cidx * 4]; w.y = u[cidx * 4 + 1]; w.z = u[cidx * 4 + 2]; w.w = u[cidx * 4 + 3];
        *(uint4*)(base + (gc ^ (t & 7)) * 8) = w;
      }
    }
  } else {
    const int hv = slot - 20;
#pragma unroll
    for (int tt = 0; tt < 2; ++tt)
#pragma unroll
      for (int jj = 0; jj < 2; ++jj) {
        int idx = jj * 256 + tid;
        int d = idx >> 3, tc = idx & 7;
        uint4 w;
        w.x = cvtpk(Cs[(tt * 64 + tc * 8 + 0) * 66 + d], Cs[(tt * 64 + tc * 8 + 1) * 66 + d]);
        w.y = cvtpk(Cs[(tt * 64 + tc * 8 + 2) * 66 + d], Cs[(tt * 64 + tc * 8 + 3) * 66 + d]);
        w.z = cvtpk(Cs[(tt * 64 + tc * 8 + 4) * 66 + d], Cs[(tt * 64 + tc * 8 + 5) * 66 + d]);
        w.w = cvtpk(Cs[(tt * 64 + tc * 8 + 6) * 66 + d], Cs[(tt * 64 + tc * 8 + 7) * 66 + d]);
        int tcs = tc ^ (d & 7);
        *(uint4*)(vt + ((size_t)hv * 64 + d) * TT + m0 + tt * 64 + tcs * 8) = w;
      }
  }
}

// C[M][N] = A[M][K] * Bt[N][K]^T ; 128x64 tile, BK=64, 4 waves, dbuf LDS (output proj).
__global__ __launch_bounds__(256) void k_gemm(const unsigned short* __restrict__ A,
                                              const unsigned short* __restrict__ Bt,
                                              float* __restrict__ C, int M, int N, int K) {
  __shared__ __attribute__((aligned(16))) unsigned short As[2][128 * 64];
  __shared__ __attribute__((aligned(16))) unsigned short Bs[2][64 * 64];
  const int tid = threadIdx.x;
  const int m0 = blockIdx.y * 128, n0 = blockIdx.x * 64;
  const int wid = tid >> 6, lane = tid & 63;
  const int g = lane >> 4, qi = lane & 15;
  const int wr = wid >> 1, wc = wid & 1;
  const int srow = lane >> 3, schk = lane & 7;
  f32x4 acc[4][2] = {};
  const int nkt = K >> 6;

  auto STAGE = [&](int b, int k0) {
#pragma unroll
    for (int j = 0; j < 4; ++j) {
      int ra = j * 32 + wid * 8 + srow;
      gload16(A + (size_t)(m0 + ra) * K + k0 + schk * 8,
              (char*)&As[b][0] + j * 4096 + (wid << 10));
    }
#pragma unroll
    for (int j = 0; j < 2; ++j) {
      int rb = j * 32 + wid * 8 + srow;
      gload16(Bt + (size_t)(n0 + rb) * K + k0 + schk * 8,
              (char*)&Bs[b][0] + j * 4096 + (wid << 10));
    }
  };

  STAGE(0, 0);
  __syncthreads();
  int cur = 0;
  for (int kt = 0; kt < nkt; ++kt) {
    if (kt + 1 < nkt) STAGE(cur ^ 1, (kt + 1) << 6);
#pragma unroll
    for (int kh = 0; kh < 2; ++kh) {
      s16x8 af[4], bq[2];
#pragma unroll
      for (int i = 0; i < 4; ++i) {
        int rA = wr * 64 + i * 16 + qi;
        af[i] = *(const s16x8*)((const char*)&As[cur][0] + rA * 128 + ((((kh << 2) | g) ^ (rA & 7)) << 4));
      }
#pragma unroll
      for (int jn = 0; jn < 2; ++jn) {
        int rB = wc * 32 + jn * 16 + qi;
        bq[jn] = *(const s16x8*)((const char*)&Bs[cur][0] + rB * 128 + ((((kh << 2) | g) ^ (rB & 7)) << 4));
      }
      __builtin_amdgcn_s_setprio(1);
#pragma unroll
      for (int i = 0; i < 4; ++i)
#pragma unroll
        for (int jn = 0; jn < 2; ++jn)
          acc[i][jn] = __builtin_amdgcn_mfma_f32_16x16x32_bf16(af[i], bq[jn], acc[i][jn], 0, 0, 0);
      __builtin_amdgcn_s_setprio(0);
    }
    __syncthreads();
    cur ^= 1;
  }
#pragma unroll
  for (int i = 0; i < 4; ++i)
#pragma unroll
    for (int jn = 0; jn < 2; ++jn) {
      int row = m0 + wr * 64 + i * 16 + g * 4;
      int col = n0 + wc * 32 + jn * 16 + qi;
#pragma unroll
      for (int r = 0; r < 4; ++r)
        C[(size_t)(row + r) * N + col] = acc[i][jn][r];
    }
}

// Flash attention, causal GQA — R5's proven 8-wave x 16q inner loop; work unit =
// (head, 128-row band, kv-HALF): 1024 blocks, longest-first per XCD, 40960B LDS ->
// 4 blocks/CU. launch_bounds(512,4): VGPR cap 128 (R14's (512,8) forced 32 VGPR ->
// 750MB scratch spill; this inner loop needs ~52). Fixed-max softmax; O/l merged via
// f32 atomicAdd (exactly 2 deterministic contributions per address, R13/R14-verified).
__global__ __launch_bounds__(512, 4) void k_attn(const unsigned short* __restrict__ q,
                                                 const unsigned short* __restrict__ kk,
                                                 const unsigned short* __restrict__ vt,
                                                 float* __restrict__ obuf,
                                                 float* __restrict__ lbuf) {
  __shared__ __attribute__((aligned(16))) char smem[40960];  // K dbuf 16K @0, V dbuf 16K @16384, P 8K @32768
  const int tid = threadIdx.x;
  const int wid = tid >> 6, lane = tid & 63, g = lane >> 4, qi = lane & 15;
  const int bid = blockIdx.x;
  const int xcd = bid & 7;
  const int rem = bid >> 3;                  // [0,128) per XCD
  const int b_ord = rem >> 2, sub = rem & 3;
  const int head = xcd * 2 + (sub >> 1);     // 2 heads per XCD (KV L2-resident)
  const int half = sub & 1;
  const int band = 31 - b_ord;               // longest-first
  const int len = band + 1;
  const int kvlo = half * len;
  const int hv = head >> 2;
  char* pb = smem + 32768 + (wid << 10);

  auto STAGE = [&](int b, int kvt) {
    const int row = tid >> 3, ch = tid & 7;
    gload16(kk + ((size_t)hv * TT + kvt * 64 + row) * 64 + ch * 8,
            smem + b * 8192 + tid * 16);
    gload16(vt + ((size_t)hv * 64 + row) * TT + kvt * 64 + ch * 8,
            smem + 16384 + b * 8192 + tid * 16);
  };

  const int qg = band * 128 + wid * 16 + qi;
  const int diagT = 2 * band + (wid >> 2);
  s16x8 qf[2];
#pragma unroll
  for (int kh = 0; kh < 2; ++kh)
    qf[kh] = *(const s16x8*)(q + ((size_t)head * TT + qg) * 64 + kh * 32 + g * 8);
  f32x4 acc[4] = {};
  float l0 = 0.0f, l1 = 0.0f;

  STAGE(0, kvlo);
  __syncthreads();
  int cur = 0;
  for (int ss = 0; ss < len; ++ss) {
    if (ss + 1 < len) STAGE(cur ^ 1, kvlo + ss + 1);
    const int kvt = kvlo + ss;
    if (kvt <= diagT) {
      const int kv0 = kvt * 64;
      const char* Kb = smem + cur * 8192;
      const char* Vb = smem + 16384 + cur * 8192;
      f32x4 sacc[4] = {};
#pragma unroll
      for (int kh = 0; kh < 2; ++kh) {
        s16x8 kf[4];
#pragma unroll
        for (int cf = 0; cf < 4; ++cf) {
          int row = cf * 16 + qi;
          kf[cf] = *(const s16x8*)(Kb + row * 128 + ((((kh << 2) | g) ^ (row & 7)) << 4));
        }
        __builtin_amdgcn_s_setprio(1);
#pragma unroll
        for (int cf = 0; cf < 4; ++cf)
          sacc[cf] = __builtin_amdgcn_mfma_f32_16x16x32_bf16(kf[cf], qf[kh], sacc[cf], 0, 0, 0);
        __builtin_amdgcn_s_setprio(0);
      }
      float pv[16];
      if (kvt == diagT) {
#pragma unroll
        for (int cf = 0; cf < 4; ++cf)
#pragma unroll
          for (int r = 0; r < 4; ++r) {
            float v = sacc[cf][r];
            if ((kv0 + cf * 16 + g * 4 + r) > qg) v = -1e30f;
            pv[cf * 4 + r] = v;
          }
      } else {
#pragma unroll
        for (int cf = 0; cf < 4; ++cf)
#pragma unroll
          for (int r = 0; r < 4; ++r) pv[cf * 4 + r] = sacc[cf][r];
      }
#pragma unroll
      for (int i = 0; i < 8; ++i) {
        float e0 = exp2f(pv[2 * i]), e1 = exp2f(pv[2 * i + 1]);
        pv[2 * i] = e0; pv[2 * i + 1] = e1;
        l0 += e0; l1 += e1;
      }
      // per-kh: write P half (16q x 32kv, 1KB), read pf, PV MFMA
#pragma unroll
      for (int kh = 0; kh < 2; ++kh) {
#pragma unroll
        for (int cl = 0; cl < 2; ++cl) {
          int cf = 2 * kh + cl;
          uint2 pw;
          pw.x = cvtpk(pv[cf * 4 + 0], pv[cf * 4 + 1]);
          pw.y = cvtpk(pv[cf * 4 + 2], pv[cf * 4 + 3]);
          *(uint2*)(pb + qi * 64 + cl * 32 + g * 8) = pw;
        }
        s16x8 pf = *(const s16x8*)(pb + qi * 64 + g * 16);
        s16x8 vf[4];
#pragma unroll
        for (int cf = 0; cf < 4; ++cf) {
          int row = cf * 16 + qi;
          vf[cf] = *(const s16x8*)(Vb + row * 128 + ((((kh << 2) | g) ^ (row & 7)) << 4));
        }
        __builtin_amdgcn_s_setprio(1);
#pragma unroll
        for (int cf = 0; cf < 4; ++cf)
          acc[cf] = __builtin_amdgcn_mfma_f32_16x16x32_bf16(vf[cf], pf, acc[cf], 0, 0, 0);
        __builtin_amdgcn_s_setprio(0);
      }
    }
    __syncthreads();
    cur ^= 1;
  }
  // flush unnormalized partials (2 contributions per address: the two kv-halves)
  float l_run = l0 + l1;
  l_run += __shfl_xor(l_run, 16);
  l_run += __shfl_xor(l_run, 32);
  if (lane < 16)
    unsafeAtomicAdd(lbuf + (size_t)head * TT + band * 128 + wid * 16 + qi, l_run);
#pragma unroll
  for (int cf = 0; cf < 4; ++cf)
#pragma unroll
    for (int r = 0; r < 4; ++r)
      unsafeAtomicAdd(obuf + (size_t)qg * 1024 + head * 64 + cf * 16 + g * 4 + r, acc[cf][r]);
}

// O = obuf / l, packed to bf16 obf (chunk-swizzled [t][1024], gemm2 A layout)
__global__ void k_norm(const float* __restrict__ obuf, const float* __restrict__ lbuf,
                       unsigned short* __restrict__ obf) {
  int idx = blockIdx.x * 256 + threadIdx.x;   // T*128
  int t = idx >> 7, kc = idx & 127;
  const float4* src = (const float4*)(obuf + (size_t)t * 1024 + kc * 8);
  float inv = 1.0f / lbuf[(size_t)(kc >> 3) * TT + t];
  float4 a = src[0], b = src[1];
  uint4 w;
  w.x = cvtpk(a.x * inv, a.y * inv); w.y = cvtpk(a.z * inv, a.w * inv);
  w.z = cvtpk(b.x * inv, b.y * inv); w.w = cvtpk(b.z * inv, b.w * inv);
  int kcs = (kc & ~7) | ((kc & 7) ^ (t & 7));
  *(uint4*)(obf + (size_t)t * 1024 + kcs * 8) = w;
}

extern "C" void kernel_launch(void* const* d_in, const int* in_sizes, int n_in,
                              void* d_out, int out_size, void* d_ws, size_t ws_size,
                              hipStream_t stream) {
  const float* hs   = (const float*)d_in[0];
  const float* cosb = (const float*)d_in[1];
  const float* sinb = (const float*)d_in[2];
  const float* Wq   = (const float*)d_in[3];
  const float* Wk   = (const float*)d_in[4];
  const float* Wv   = (const float*)d_in[5];
  const float* Wo   = (const float*)d_in[6];
  const float* qw   = (const float*)d_in[7];
  const float* kw   = (const float*)d_in[8];
  char* ws = (char*)d_ws;
  unsigned short* hs_swz = (unsigned short*)(ws + OFF_HS);
  unsigned short* wqkv   = (unsigned short*)(ws + OFF_WQKV);
  float*          obuf   = (float*)(ws + OFF_OBUF);
  float*          lbuf   = (float*)(ws + OFF_LBUF);
  unsigned short* wo_t   = (unsigned short*)(ws + OFF_WO);
  unsigned short* qbf    = (unsigned short*)(ws + OFF_Q);
  unsigned short* kbf    = (unsigned short*)(ws + OFF_K);
  unsigned short* vtb    = (unsigned short*)(ws + OFF_VT);
  unsigned short* obf    = (unsigned short*)(ws + OFF_O);

  k_convert_hs<<<2048, 256, 0, stream>>>(hs, hs_swz);
  k_convert_w_all<<<1280, 256, 0, stream>>>(Wq, Wk, Wv, Wo, wqkv, wo_t);
  k_gemm_qkv<<<dim3(24, 32), 256, 0, stream>>>(hs_swz, wqkv, cosb, sinb, qw, kw, qbf, kbf, vtb);
  hipMemsetAsync(obuf, 0, (size_t)4096 * 1024 * 4, stream);   // overlays dead hs_swz/wqkv
  hipMemsetAsync(lbuf, 0, (size_t)16 * 4096 * 4, stream);
  k_attn<<<1024, 512, 0, stream>>>(qbf, kbf, vtb, obuf, lbuf);
  k_norm<<<2048, 256, 0, stream>>>(obuf, lbuf, obf);
  k_gemm<<<dim3(16, 32), 256, 0, stream>>>(obf, wo_t, (float*)d_out, 4096, 1024, 1024);
}

// Round 16
// 133.635 us; speedup vs baseline: 2.1537x; 1.6400x over previous
//
#include <hip/hip_runtime.h>
#include <stdint.h>

#define TT 4096
#define HIDD 1024

typedef __attribute__((ext_vector_type(4))) float f32x4;
typedef __attribute__((ext_vector_type(8))) short s16x8;

static constexpr float kEps = 1e-6f;
static constexpr float kCsc = 0.125f * 1.44269504088896f;  // scale * log2(e), folded into q

// ---- workspace layout (bytes) ----
static constexpr size_t OFF_HS   = 0;          // bf16 hs swz [4096][1024] 8 MB
static constexpr size_t OFF_WQKV = 8388608;    // bf16 WqkvT  [1536][1024] 3 MB
static constexpr size_t OFF_WO   = 11534336;   // bf16 WoT [1024][1024] 2 MB
static constexpr size_t OFF_Q    = 13631488;   // bf16 q [16][4096][64] 8 MB
static constexpr size_t OFF_K    = 22020096;   // bf16 k swz [4][4096][64] 2 MB
static constexpr size_t OFF_O    = 24117248;   // bf16 attn-out swz [4096][1024] 8 MB
static constexpr size_t OFF_VT   = 38797312;   // bf16 vT swz [4][64][4096] 2 MB

__device__ __forceinline__ unsigned int pk_bf16(float a, float b) {
  union { float f; unsigned int u; } x, y;
  x.f = a; y.f = b;
  unsigned int lo = (x.u + 0x7fffu + ((x.u >> 16) & 1u)) >> 16;
  unsigned int hi = (y.u + 0x7fffu + ((y.u >> 16) & 1u)) >> 16;
  return (lo & 0xffffu) | (hi << 16);
}
__device__ __forceinline__ unsigned int cvtpk(float lo, float hi) {
  unsigned int r;
  asm("v_cvt_pk_bf16_f32 %0, %1, %2" : "=v"(r) : "v"(lo), "v"(hi));
  return r;
}
__device__ __forceinline__ void gload16(const void* g, void* l) {
  __builtin_amdgcn_global_load_lds(
      (const __attribute__((address_space(1))) unsigned int*)g,
      (__attribute__((address_space(3))) unsigned int*)l, 16, 0, 0);
}

// hs fp32 [T][1024] -> bf16 swizzled (16B chunk index XORed by row&7 within 64-elem groups)
__global__ void k_convert_hs(const float* __restrict__ hs, unsigned short* __restrict__ out) {
  int idx = blockIdx.x * 256 + threadIdx.x;  // T*128
  int t = idx >> 7, kc = idx & 127;
  const float4* src = (const float4*)(hs + (size_t)t * HIDD + kc * 8);
  float4 a = src[0], b = src[1];
  int kcs = (kc & ~7) | ((kc & 7) ^ (t & 7));
  uint4 w;
  w.x = pk_bf16(a.x, a.y); w.y = pk_bf16(a.z, a.w);
  w.z = pk_bf16(b.x, b.y); w.w = pk_bf16(b.z, b.w);
  *(uint4*)(out + (size_t)t * HIDD + kcs * 8) = w;
}

// All four weight matrices: fp32 [1024][ncols] -> bf16 W^T [ncols][1024] swizzled by n&7
__global__ void k_convert_w_all(const float* __restrict__ Wq, const float* __restrict__ Wk,
                                const float* __restrict__ Wv, const float* __restrict__ Wo,
                                unsigned short* __restrict__ wqkv, unsigned short* __restrict__ wo_t) {
  int b = blockIdx.x, tid = threadIdx.x;
  const float* W; unsigned short* outT; int nshift, idx;
  if (b < 512)      { W = Wq; outT = wqkv;                nshift = 10; idx = b * 256 + tid; }
  else if (b < 640) { W = Wk; outT = wqkv + 1024 * 1024;  nshift = 8;  idx = (b - 512) * 256 + tid; }
  else if (b < 768) { W = Wv; outT = wqkv + 1280 * 1024;  nshift = 8;  idx = (b - 640) * 256 + tid; }
  else              { W = Wo; outT = wo_t;                nshift = 10; idx = (b - 768) * 256 + tid; }
  int ncols = 1 << nshift;
  int kc = idx >> nshift, n = idx & (ncols - 1);
  float v[8];
#pragma unroll
  for (int e = 0; e < 8; ++e) v[e] = W[(size_t)(kc * 8 + e) * ncols + n];
  int kcs = (kc & ~7) | ((kc & 7) ^ (n & 7));
  uint4 w;
  w.x = pk_bf16(v[0], v[1]); w.y = pk_bf16(v[2], v[3]);
  w.z = pk_bf16(v[4], v[5]); w.w = pk_bf16(v[6], v[7]);
  *(uint4*)(outT + (size_t)n * HIDD + kcs * 8) = w;
}

// Fused QKV GEMM + RMSNorm + RoPE + bf16 layout conversion (R12, verified).
__global__ __launch_bounds__(256) void k_gemm_qkv(const unsigned short* __restrict__ A,
                                                  const unsigned short* __restrict__ Bt,
                                                  const float* __restrict__ cosb,
                                                  const float* __restrict__ sinb,
                                                  const float* __restrict__ qw,
                                                  const float* __restrict__ kw,
                                                  unsigned short* __restrict__ qo,
                                                  unsigned short* __restrict__ ko,
                                                  unsigned short* __restrict__ vt) {
  __shared__ __attribute__((aligned(16))) char smem[49152];
  const int K = HIDD;
  const int tid = threadIdx.x;
  const int m0 = blockIdx.y * 128, slot = blockIdx.x, n0 = slot * 64;
  const int wid = tid >> 6, lane = tid & 63;
  const int g = lane >> 4, qi = lane & 15;
  const int wr = wid >> 1, wc = wid & 1;
  const int srow = lane >> 3, schk = lane & 7;
  f32x4 acc[4][2] = {};
  const int nkt = K >> 6;

  auto STAGE = [&](int b, int k0) {
#pragma unroll
    for (int j = 0; j < 4; ++j) {
      int ra = j * 32 + wid * 8 + srow;
      gload16(A + (size_t)(m0 + ra) * K + k0 + schk * 8,
              smem + b * 16384 + j * 4096 + (wid << 10));
    }
#pragma unroll
    for (int j = 0; j < 2; ++j) {
      int rb = j * 32 + wid * 8 + srow;
      gload16(Bt + (size_t)(n0 + rb) * K + k0 + schk * 8,
              smem + 32768 + b * 8192 + j * 4096 + (wid << 10));
    }
  };

  STAGE(0, 0);
  __syncthreads();
  int cur = 0;
  for (int kt = 0; kt < nkt; ++kt) {
    if (kt + 1 < nkt) STAGE(cur ^ 1, (kt + 1) << 6);
#pragma unroll
    for (int kh = 0; kh < 2; ++kh) {
      s16x8 af[4], bq[2];
#pragma unroll
      for (int i = 0; i < 4; ++i) {
        int rA = wr * 64 + i * 16 + qi;
        af[i] = *(const s16x8*)(smem + cur * 16384 + rA * 128 + ((((kh << 2) | g) ^ (rA & 7)) << 4));
      }
#pragma unroll
      for (int jn = 0; jn < 2; ++jn) {
        int rB = wc * 32 + jn * 16 + qi;
        bq[jn] = *(const s16x8*)(smem + 32768 + cur * 8192 + rB * 128 + ((((kh << 2) | g) ^ (rB & 7)) << 4));
      }
      __builtin_amdgcn_s_setprio(1);
#pragma unroll
      for (int i = 0; i < 4; ++i)
#pragma unroll
        for (int jn = 0; jn < 2; ++jn)
          acc[i][jn] = __builtin_amdgcn_mfma_f32_16x16x32_bf16(af[i], bq[jn], acc[i][jn], 0, 0, 0);
      __builtin_amdgcn_s_setprio(0);
    }
    __syncthreads();
    cur ^= 1;
  }

  // ---- epilogue ----
  float* Cs = (float*)smem;                 // [128][66] f32
#pragma unroll
  for (int i = 0; i < 4; ++i)
#pragma unroll
    for (int jn = 0; jn < 2; ++jn) {
      int row = wr * 64 + i * 16 + g * 4;
      int col = wc * 32 + jn * 16 + qi;
#pragma unroll
      for (int r = 0; r < 4; ++r)
        Cs[(row + r) * 66 + col] = acc[i][jn][r];
    }
  __syncthreads();

  if (slot < 20) {
    const int lr = tid >> 1, hf = tid & 1;
    const int t = m0 + lr;
    const float* self_p = Cs + lr * 66 + hf * 32;
    const float* oth_p  = Cs + lr * 66 + (1 - hf) * 32;
    float ss = 0.0f;
#pragma unroll
    for (int e = 0; e < 32; ++e) { float v = self_p[e]; ss += v * v; }
    ss += __shfl_xor(ss, 1);
    const float rms = rsqrtf(ss * (1.0f / 64.0f) + kEps);
    const float* wvec = (slot < 16) ? qw : kw;
    const float outscale = (slot < 16) ? kCsc : 1.0f;
    unsigned int u[16];
#pragma unroll
    for (int ee = 0; ee < 16; ++ee) {
      float o2[2];
#pragma unroll
      for (int p = 0; p < 2; ++p) {
        int e = 2 * ee + p;
        float c = cosb[t * 32 + e];
        float s = sinb[t * 32 + e];
        float self = self_p[e] * rms * wvec[hf * 32 + e];
        float oth  = oth_p[e]  * rms * wvec[(1 - hf) * 32 + e];
        float r = hf ? (oth * s + self * c) : (self * c - oth * s);
        o2[p] = r * outscale;
      }
      u[ee] = cvtpk(o2[0], o2[1]);
    }
    if (slot < 16) {
      unsigned short* base = qo + ((size_t)slot * TT + t) * 64 + hf * 32;
#pragma unroll
      for (int cidx = 0; cidx < 4; ++cidx) {
        uint4 w; w.x = u[cidx * 4]; w.y = u[cidx * 4 + 1]; w.z = u[cidx * 4 + 2]; w.w = u[cidx * 4 + 3];
        *(uint4*)(base + cidx * 8) = w;
      }
    } else {
      const int hv = slot - 16;
      unsigned short* base = ko + ((size_t)hv * TT + t) * 64;
#pragma unroll
      for (int cidx = 0; cidx < 4; ++cidx) {
        int gc = hf * 4 + cidx;
        uint4 w; w.x = u[cidx * 4]; w.y = u[cidx * 4 + 1]; w.z = u[cidx * 4 + 2]; w.w = u[cidx * 4 + 3];
        *(uint4*)(base + (gc ^ (t & 7)) * 8) = w;
      }
    }
  } else {
    const int hv = slot - 20;
#pragma unroll
    for (int tt = 0; tt < 2; ++tt)
#pragma unroll
      for (int jj = 0; jj < 2; ++jj) {
        int idx = jj * 256 + tid;
        int d = idx >> 3, tc = idx & 7;
        uint4 w;
        w.x = cvtpk(Cs[(tt * 64 + tc * 8 + 0) * 66 + d], Cs[(tt * 64 + tc * 8 + 1) * 66 + d]);
        w.y = cvtpk(Cs[(tt * 64 + tc * 8 + 2) * 66 + d], Cs[(tt * 64 + tc * 8 + 3) * 66 + d]);
        w.z = cvtpk(Cs[(tt * 64 + tc * 8 + 4) * 66 + d], Cs[(tt * 64 + tc * 8 + 5) * 66 + d]);
        w.w = cvtpk(Cs[(tt * 64 + tc * 8 + 6) * 66 + d], Cs[(tt * 64 + tc * 8 + 7) * 66 + d]);
        int tcs = tc ^ (d & 7);
        *(uint4*)(vt + ((size_t)hv * 64 + d) * TT + m0 + tt * 64 + tcs * 8) = w;
      }
  }
}

// C[M][N] = A[M][K] * Bt[N][K]^T ; 128x64 tile, BK=64, 4 waves, dbuf LDS (output proj).
__global__ __launch_bounds__(256) void k_gemm(const unsigned short* __restrict__ A,
                                              const unsigned short* __restrict__ Bt,
                                              float* __restrict__ C, int M, int N, int K) {
  __shared__ __attribute__((aligned(16))) unsigned short As[2][128 * 64];
  __shared__ __attribute__((aligned(16))) unsigned short Bs[2][64 * 64];
  const int tid = threadIdx.x;
  const int m0 = blockIdx.y * 128, n0 = blockIdx.x * 64;
  const int wid = tid >> 6, lane = tid & 63;
  const int g = lane >> 4, qi = lane & 15;
  const int wr = wid >> 1, wc = wid & 1;
  const int srow = lane >> 3, schk = lane & 7;
  f32x4 acc[4][2] = {};
  const int nkt = K >> 6;

  auto STAGE = [&](int b, int k0) {
#pragma unroll
    for (int j = 0; j < 4; ++j) {
      int ra = j * 32 + wid * 8 + srow;
      gload16(A + (size_t)(m0 + ra) * K + k0 + schk * 8,
              (char*)&As[b][0] + j * 4096 + (wid << 10));
    }
#pragma unroll
    for (int j = 0; j < 2; ++j) {
      int rb = j * 32 + wid * 8 + srow;
      gload16(Bt + (size_t)(n0 + rb) * K + k0 + schk * 8,
              (char*)&Bs[b][0] + j * 4096 + (wid << 10));
    }
  };

  STAGE(0, 0);
  __syncthreads();
  int cur = 0;
  for (int kt = 0; kt < nkt; ++kt) {
    if (kt + 1 < nkt) STAGE(cur ^ 1, (kt + 1) << 6);
#pragma unroll
    for (int kh = 0; kh < 2; ++kh) {
      s16x8 af[4], bq[2];
#pragma unroll
      for (int i = 0; i < 4; ++i) {
        int rA = wr * 64 + i * 16 + qi;
        af[i] = *(const s16x8*)((const char*)&As[cur][0] + rA * 128 + ((((kh << 2) | g) ^ (rA & 7)) << 4));
      }
#pragma unroll
      for (int jn = 0; jn < 2; ++jn) {
        int rB = wc * 32 + jn * 16 + qi;
        bq[jn] = *(const s16x8*)((const char*)&Bs[cur][0] + rB * 128 + ((((kh << 2) | g) ^ (rB & 7)) << 4));
      }
      __builtin_amdgcn_s_setprio(1);
#pragma unroll
      for (int i = 0; i < 4; ++i)
#pragma unroll
        for (int jn = 0; jn < 2; ++jn)
          acc[i][jn] = __builtin_amdgcn_mfma_f32_16x16x32_bf16(af[i], bq[jn], acc[i][jn], 0, 0, 0);
      __builtin_amdgcn_s_setprio(0);
    }
    __syncthreads();
    cur ^= 1;
  }
#pragma unroll
  for (int i = 0; i < 4; ++i)
#pragma unroll
    for (int jn = 0; jn < 2; ++jn) {
      int row = m0 + wr * 64 + i * 16 + g * 4;
      int col = n0 + wc * 32 + jn * 16 + qi;
#pragma unroll
      for (int r = 0; r < 4; ++r)
        C[(size_t)(row + r) * N + col] = acc[i][jn][r];
    }
}

// Flash attention, causal GQA — R5's verified 16q inner loop; ONE 64-row q-tile per
// block, 4 waves x 16q (all share the block diag -> 100% wave activity, no idle
// pairing). 1024 blocks; LDS = K dbuf 16K + V dbuf 16K + P 4x2K = 40960B exactly
// -> 4 blocks/CU, grid = 4.0/CU even -> 16 waves/CU resident, all active.
// Longest-first within each XCD (2 heads/XCD, KV L2-resident), 4-deep per-CU queue
// smooths the [1..64]-step extent spread. Fixed-max exp2 softmax (q pre-scaled).
__global__ __launch_bounds__(256) void k_attn(const unsigned short* __restrict__ q,
                                              const unsigned short* __restrict__ kk,
                                              const unsigned short* __restrict__ vt,
                                              unsigned short* __restrict__ o) {
  __shared__ __attribute__((aligned(16))) unsigned short Kl[2][64 * 64];
  __shared__ __attribute__((aligned(16))) unsigned short Vl[2][64 * 64];
  __shared__ __attribute__((aligned(16))) unsigned short Pl[4][1024];
  const int tid = threadIdx.x;
  const int wid = tid >> 6, lane = tid & 63, g = lane >> 4, qi = lane & 15;
  const int bid = blockIdx.x;
  const int xcd = bid & 7;
  const int rem = bid >> 3;                  // [0,128) per XCD
  const int head = xcd * 2 + (rem & 1);      // 2 heads per XCD (same KV group, L2-resident)
  const int qt = 63 - (rem >> 1);            // longest tiles first
  const int hv = head >> 2;
  char* pb = (char*)&Pl[wid][0];

  auto STAGE = [&](int b, int s) {
    const int kv0 = s * 64;
#pragma unroll
    for (int p = 0; p < 2; ++p) {
      int c = tid + p * 256;
      int r = c >> 3, ch8 = (c & 7) * 8;
      gload16(kk + ((size_t)hv * TT + kv0 + r) * 64 + ch8, (char*)&Kl[b][0] + c * 16);
      gload16(vt + ((size_t)hv * 64 + r) * TT + kv0 + ch8, (char*)&Vl[b][0] + c * 16);
    }
  };

  const int qg = qt * 64 + wid * 16 + qi;
  s16x8 qf[2];
#pragma unroll
  for (int kh = 0; kh < 2; ++kh)
    qf[kh] = *(const s16x8*)(q + ((size_t)head * TT + qg) * 64 + kh * 32 + g * 8);
  f32x4 acc[4] = {};
  float l0 = 0.0f, l1 = 0.0f;

  STAGE(0, 0);
  __syncthreads();
  int cur = 0;
  for (int s = 0; s <= qt; ++s) {
    if (s < qt) STAGE(cur ^ 1, s + 1);
    const int kv0 = s * 64;
    f32x4 sacc[4] = {};
#pragma unroll
    for (int kh = 0; kh < 2; ++kh) {
      s16x8 kf[4];
#pragma unroll
      for (int cf = 0; cf < 4; ++cf) {
        int row = cf * 16 + qi;
        kf[cf] = *(const s16x8*)((const char*)&Kl[cur][0] + row * 128 + ((((kh << 2) | g) ^ (row & 7)) << 4));
      }
      __builtin_amdgcn_s_setprio(1);
#pragma unroll
      for (int cf = 0; cf < 4; ++cf)
        sacc[cf] = __builtin_amdgcn_mfma_f32_16x16x32_bf16(kf[cf], qf[kh], sacc[cf], 0, 0, 0);
      __builtin_amdgcn_s_setprio(0);
    }
    float pv[16];
    if (s == qt) {
#pragma unroll
      for (int cf = 0; cf < 4; ++cf)
#pragma unroll
        for (int r = 0; r < 4; ++r) {
          float v = sacc[cf][r];
          if ((kv0 + cf * 16 + g * 4 + r) > qg) v = -1e30f;
          pv[cf * 4 + r] = v;
        }
    } else {
#pragma unroll
      for (int cf = 0; cf < 4; ++cf)
#pragma unroll
        for (int r = 0; r < 4; ++r) pv[cf * 4 + r] = sacc[cf][r];
    }
#pragma unroll
    for (int i = 0; i < 8; ++i) {
      float e0 = exp2f(pv[2 * i]), e1 = exp2f(pv[2 * i + 1]);
      pv[2 * i] = e0; pv[2 * i + 1] = e1;
      l0 += e0; l1 += e1;
    }
#pragma unroll
    for (int cf = 0; cf < 4; ++cf) {
      int chunk = cf * 2 + (g >> 1);
      int base = qi * 128 + ((chunk ^ (qi & 7)) << 4) + ((g & 1) << 3);
      uint2 pw;
      pw.x = cvtpk(pv[cf * 4 + 0], pv[cf * 4 + 1]);
      pw.y = cvtpk(pv[cf * 4 + 2], pv[cf * 4 + 3]);
      *(uint2*)(pb + base) = pw;
    }
#pragma unroll
    for (int kh = 0; kh < 2; ++kh) {
      s16x8 pf = *(const s16x8*)(pb + qi * 128 + ((((kh << 2) | g) ^ (qi & 7)) << 4));
      s16x8 vf[4];
#pragma unroll
      for (int cf = 0; cf < 4; ++cf) {
        int row = cf * 16 + qi;
        vf[cf] = *(const s16x8*)((const char*)&Vl[cur][0] + row * 128 + ((((kh << 2) | g) ^ (row & 7)) << 4));
      }
      __builtin_amdgcn_s_setprio(1);
#pragma unroll
      for (int cf = 0; cf < 4; ++cf)
        acc[cf] = __builtin_amdgcn_mfma_f32_16x16x32_bf16(vf[cf], pf, acc[cf], 0, 0, 0);
      __builtin_amdgcn_s_setprio(0);
    }
    __syncthreads();
    cur ^= 1;
  }
  float l_run = l0 + l1;
  l_run += __shfl_xor(l_run, 16);
  l_run += __shfl_xor(l_run, 32);
  float inv = 1.0f / l_run;
#pragma unroll
  for (int cf = 0; cf < 4; ++cf) {
    int col = head * 64 + cf * 16 + g * 4;
    int chunk = col >> 3;
    int chs = (chunk & ~7) | ((chunk & 7) ^ (qg & 7));
    char* ob = (char*)o + (size_t)qg * 2048 + (chs << 4) + ((g & 1) << 3);
    *(unsigned int*)ob = cvtpk(acc[cf][0] * inv, acc[cf][1] * inv);
    *(unsigned int*)(ob + 4) = cvtpk(acc[cf][2] * inv, acc[cf][3] * inv);
  }
}

extern "C" void kernel_launch(void* const* d_in, const int* in_sizes, int n_in,
                              void* d_out, int out_size, void* d_ws, size_t ws_size,
                              hipStream_t stream) {
  const float* hs   = (const float*)d_in[0];
  const float* cosb = (const float*)d_in[1];
  const float* sinb = (const float*)d_in[2];
  const float* Wq   = (const float*)d_in[3];
  const float* Wk   = (const float*)d_in[4];
  const float* Wv   = (const float*)d_in[5];
  const float* Wo   = (const float*)d_in[6];
  const float* qw   = (const float*)d_in[7];
  const float* kw   = (const float*)d_in[8];
  char* ws = (char*)d_ws;
  unsigned short* hs_swz = (unsigned short*)(ws + OFF_HS);
  unsigned short* wqkv   = (unsigned short*)(ws + OFF_WQKV);
  unsigned short* wo_t   = (unsigned short*)(ws + OFF_WO);
  unsigned short* qbf    = (unsigned short*)(ws + OFF_Q);
  unsigned short* kbf    = (unsigned short*)(ws + OFF_K);
  unsigned short* vtb    = (unsigned short*)(ws + OFF_VT);
  unsigned short* obf    = (unsigned short*)(ws + OFF_O);

  k_convert_hs<<<2048, 256, 0, stream>>>(hs, hs_swz);
  k_convert_w_all<<<1280, 256, 0, stream>>>(Wq, Wk, Wv, Wo, wqkv, wo_t);
  k_gemm_qkv<<<dim3(24, 32), 256, 0, stream>>>(hs_swz, wqkv, cosb, sinb, qw, kw, qbf, kbf, vtb);
  k_attn<<<1024, 256, 0, stream>>>(qbf, kbf, vtb, obf);
  k_gemm<<<dim3(16, 32), 256, 0, stream>>>(obf, wo_t, (float*)d_out, 4096, 1024, 1024);
}

// Round 18
// 133.130 us; speedup vs baseline: 2.1619x; 1.0038x over previous
//
#include <hip/hip_runtime.h>
#include <stdint.h>

#define TT 4096
#define HIDD 1024

typedef __attribute__((ext_vector_type(4))) float f32x4;
typedef __attribute__((ext_vector_type(8))) short s16x8;

static constexpr float kEps = 1e-6f;
static constexpr float kCsc = 0.125f * 1.44269504088896f;  // scale * log2(e), folded into q

// ---- workspace layout (bytes) ----
static constexpr size_t OFF_HS   = 0;          // bf16 hs swz [4096][1024] 8 MB
static constexpr size_t OFF_WQKV = 8388608;    // bf16 WqkvT  [1536][1024] 3 MB
static constexpr size_t OFF_WO   = 11534336;   // bf16 WoT [1024][1024] 2 MB
static constexpr size_t OFF_Q    = 13631488;   // bf16 q [16][4096][64] 8 MB
static constexpr size_t OFF_K    = 22020096;   // bf16 k swz [4][4096][64] 2 MB
static constexpr size_t OFF_O    = 24117248;   // bf16 attn-out swz [4096][1024] 8 MB
static constexpr size_t OFF_VT   = 38797312;   // bf16 vT swz [4][64][4096] 2 MB

__device__ __forceinline__ unsigned int pk_bf16(float a, float b) {
  union { float f; unsigned int u; } x, y;
  x.f = a; y.f = b;
  unsigned int lo = (x.u + 0x7fffu + ((x.u >> 16) & 1u)) >> 16;
  unsigned int hi = (y.u + 0x7fffu + ((y.u >> 16) & 1u)) >> 16;
  return (lo & 0xffffu) | (hi << 16);
}
__device__ __forceinline__ unsigned int cvtpk(float lo, float hi) {
  unsigned int r;
  asm("v_cvt_pk_bf16_f32 %0, %1, %2" : "=v"(r) : "v"(lo), "v"(hi));
  return r;
}
__device__ __forceinline__ void gload16(const void* g, void* l) {
  __builtin_amdgcn_global_load_lds(
      (const __attribute__((address_space(1))) unsigned int*)g,
      (__attribute__((address_space(3))) unsigned int*)l, 16, 0, 0);
}

// hs fp32 [T][1024] -> bf16 swizzled (16B chunk index XORed by row&7 within 64-elem groups)
__global__ void k_convert_hs(const float* __restrict__ hs, unsigned short* __restrict__ out) {
  int idx = blockIdx.x * 256 + threadIdx.x;  // T*128
  int t = idx >> 7, kc = idx & 127;
  const float4* src = (const float4*)(hs + (size_t)t * HIDD + kc * 8);
  float4 a = src[0], b = src[1];
  int kcs = (kc & ~7) | ((kc & 7) ^ (t & 7));
  uint4 w;
  w.x = pk_bf16(a.x, a.y); w.y = pk_bf16(a.z, a.w);
  w.z = pk_bf16(b.x, b.y); w.w = pk_bf16(b.z, b.w);
  *(uint4*)(out + (size_t)t * HIDD + kcs * 8) = w;
}

// All four weight matrices: fp32 [1024][ncols] -> bf16 W^T [ncols][1024] swizzled by n&7
__global__ void k_convert_w_all(const float* __restrict__ Wq, const float* __restrict__ Wk,
                                const float* __restrict__ Wv, const float* __restrict__ Wo,
                                unsigned short* __restrict__ wqkv, unsigned short* __restrict__ wo_t) {
  int b = blockIdx.x, tid = threadIdx.x;
  const float* W; unsigned short* outT; int nshift, idx;
  if (b < 512)      { W = Wq; outT = wqkv;                nshift = 10; idx = b * 256 + tid; }
  else if (b < 640) { W = Wk; outT = wqkv + 1024 * 1024;  nshift = 8;  idx = (b - 512) * 256 + tid; }
  else if (b < 768) { W = Wv; outT = wqkv + 1280 * 1024;  nshift = 8;  idx = (b - 640) * 256 + tid; }
  else              { W = Wo; outT = wo_t;                nshift = 10; idx = (b - 768) * 256 + tid; }
  int ncols = 1 << nshift;
  int kc = idx >> nshift, n = idx & (ncols - 1);
  float v[8];
#pragma unroll
  for (int e = 0; e < 8; ++e) v[e] = W[(size_t)(kc * 8 + e) * ncols + n];
  int kcs = (kc & ~7) | ((kc & 7) ^ (n & 7));
  uint4 w;
  w.x = pk_bf16(v[0], v[1]); w.y = pk_bf16(v[2], v[3]);
  w.z = pk_bf16(v[4], v[5]); w.w = pk_bf16(v[6], v[7]);
  *(uint4*)(outT + (size_t)n * HIDD + kcs * 8) = w;
}

// Fused QKV GEMM + RMSNorm + RoPE + bf16 layout conversion (R12, verified).
__global__ __launch_bounds__(256) void k_gemm_qkv(const unsigned short* __restrict__ A,
                                                  const unsigned short* __restrict__ Bt,
                                                  const float* __restrict__ cosb,
                                                  const float* __restrict__ sinb,
                                                  const float* __restrict__ qw,
                                                  const float* __restrict__ kw,
                                                  unsigned short* __restrict__ qo,
                                                  unsigned short* __restrict__ ko,
                                                  unsigned short* __restrict__ vt) {
  __shared__ __attribute__((aligned(16))) char smem[49152];
  const int K = HIDD;
  const int tid = threadIdx.x;
  const int m0 = blockIdx.y * 128, slot = blockIdx.x, n0 = slot * 64;
  const int wid = tid >> 6, lane = tid & 63;
  const int g = lane >> 4, qi = lane & 15;
  const int wr = wid >> 1, wc = wid & 1;
  const int srow = lane >> 3, schk = lane & 7;
  f32x4 acc[4][2] = {};
  const int nkt = K >> 6;

  auto STAGE = [&](int b, int k0) {
#pragma unroll
    for (int j = 0; j < 4; ++j) {
      int ra = j * 32 + wid * 8 + srow;
      gload16(A + (size_t)(m0 + ra) * K + k0 + schk * 8,
              smem + b * 16384 + j * 4096 + (wid << 10));
    }
#pragma unroll
    for (int j = 0; j < 2; ++j) {
      int rb = j * 32 + wid * 8 + srow;
      gload16(Bt + (size_t)(n0 + rb) * K + k0 + schk * 8,
              smem + 32768 + b * 8192 + j * 4096 + (wid << 10));
    }
  };

  STAGE(0, 0);
  __syncthreads();
  int cur = 0;
  for (int kt = 0; kt < nkt; ++kt) {
    if (kt + 1 < nkt) STAGE(cur ^ 1, (kt + 1) << 6);
#pragma unroll
    for (int kh = 0; kh < 2; ++kh) {
      s16x8 af[4], bq[2];
#pragma unroll
      for (int i = 0; i < 4; ++i) {
        int rA = wr * 64 + i * 16 + qi;
        af[i] = *(const s16x8*)(smem + cur * 16384 + rA * 128 + ((((kh << 2) | g) ^ (rA & 7)) << 4));
      }
#pragma unroll
      for (int jn = 0; jn < 2; ++jn) {
        int rB = wc * 32 + jn * 16 + qi;
        bq[jn] = *(const s16x8*)(smem + 32768 + cur * 8192 + rB * 128 + ((((kh << 2) | g) ^ (rB & 7)) << 4));
      }
      __builtin_amdgcn_s_setprio(1);
#pragma unroll
      for (int i = 0; i < 4; ++i)
#pragma unroll
        for (int jn = 0; jn < 2; ++jn)
          acc[i][jn] = __builtin_amdgcn_mfma_f32_16x16x32_bf16(af[i], bq[jn], acc[i][jn], 0, 0, 0);
      __builtin_amdgcn_s_setprio(0);
    }
    __syncthreads();
    cur ^= 1;
  }

  // ---- epilogue ----
  float* Cs = (float*)smem;                 // [128][66] f32
#pragma unroll
  for (int i = 0; i < 4; ++i)
#pragma unroll
    for (int jn = 0; jn < 2; ++jn) {
      int row = wr * 64 + i * 16 + g * 4;
      int col = wc * 32 + jn * 16 + qi;
#pragma unroll
      for (int r = 0; r < 4; ++r)
        Cs[(row + r) * 66 + col] = acc[i][jn][r];
    }
  __syncthreads();

  if (slot < 20) {
    const int lr = tid >> 1, hf = tid & 1;
    const int t = m0 + lr;
    const float* self_p = Cs + lr * 66 + hf * 32;
    const float* oth_p  = Cs + lr * 66 + (1 - hf) * 32;
    float ss = 0.0f;
#pragma unroll
    for (int e = 0; e < 32; ++e) { float v = self_p[e]; ss += v * v; }
    ss += __shfl_xor(ss, 1);
    const float rms = rsqrtf(ss * (1.0f / 64.0f) + kEps);
    const float* wvec = (slot < 16) ? qw : kw;
    const float outscale = (slot < 16) ? kCsc : 1.0f;
    unsigned int u[16];
#pragma unroll
    for (int ee = 0; ee < 16; ++ee) {
      float o2[2];
#pragma unroll
      for (int p = 0; p < 2; ++p) {
        int e = 2 * ee + p;
        float c = cosb[t * 32 + e];
        float s = sinb[t * 32 + e];
        float self = self_p[e] * rms * wvec[hf * 32 + e];
        float oth  = oth_p[e]  * rms * wvec[(1 - hf) * 32 + e];
        float r = hf ? (oth * s + self * c) : (self * c - oth * s);
        o2[p] = r * outscale;
      }
      u[ee] = cvtpk(o2[0], o2[1]);
    }
    if (slot < 16) {
      unsigned short* base = qo + ((size_t)slot * TT + t) * 64 + hf * 32;
#pragma unroll
      for (int cidx = 0; cidx < 4; ++cidx) {
        uint4 w; w.x = u[cidx * 4]; w.y = u[cidx * 4 + 1]; w.z = u[cidx * 4 + 2]; w.w = u[cidx * 4 + 3];
        *(uint4*)(base + cidx * 8) = w;
      }
    } else {
      const int hv = slot - 16;
      unsigned short* base = ko + ((size_t)hv * TT + t) * 64;
#pragma unroll
      for (int cidx = 0; cidx < 4; ++cidx) {
        int gc = hf * 4 + cidx;
        uint4 w; w.x = u[cidx * 4]; w.y = u[cidx * 4 + 1]; w.z = u[cidx * 4 + 2]; w.w = u[cidx * 4 + 3];
        *(uint4*)(base + (gc ^ (t & 7)) * 8) = w;
      }
    }
  } else {
    const int hv = slot - 20;
#pragma unroll
    for (int tt = 0; tt < 2; ++tt)
#pragma unroll
      for (int jj = 0; jj < 2; ++jj) {
        int idx = jj * 256 + tid;
        int d = idx >> 3, tc = idx & 7;
        uint4 w;
        w.x = cvtpk(Cs[(tt * 64 + tc * 8 + 0) * 66 + d], Cs[(tt * 64 + tc * 8 + 1) * 66 + d]);
        w.y = cvtpk(Cs[(tt * 64 + tc * 8 + 2) * 66 + d], Cs[(tt * 64 + tc * 8 + 3) * 66 + d]);
        w.z = cvtpk(Cs[(tt * 64 + tc * 8 + 4) * 66 + d], Cs[(tt * 64 + tc * 8 + 5) * 66 + d]);
        w.w = cvtpk(Cs[(tt * 64 + tc * 8 + 6) * 66 + d], Cs[(tt * 64 + tc * 8 + 7) * 66 + d]);
        int tcs = tc ^ (d & 7);
        *(uint4*)(vt + ((size_t)hv * 64 + d) * TT + m0 + tt * 64 + tcs * 8) = w;
      }
  }
}

// C[M][N] = A[M][K] * Bt[N][K]^T ; 128x64 tile, BK=64, 4 waves, dbuf LDS (output proj).
__global__ __launch_bounds__(256) void k_gemm(const unsigned short* __restrict__ A,
                                              const unsigned short* __restrict__ Bt,
                                              float* __restrict__ C, int M, int N, int K) {
  __shared__ __attribute__((aligned(16))) unsigned short As[2][128 * 64];
  __shared__ __attribute__((aligned(16))) unsigned short Bs[2][64 * 64];
  const int tid = threadIdx.x;
  const int m0 = blockIdx.y * 128, n0 = blockIdx.x * 64;
  const int wid = tid >> 6, lane = tid & 63;
  const int g = lane >> 4, qi = lane & 15;
  const int wr = wid >> 1, wc = wid & 1;
  const int srow = lane >> 3, schk = lane & 7;
  f32x4 acc[4][2] = {};
  const int nkt = K >> 6;

  auto STAGE = [&](int b, int k0) {
#pragma unroll
    for (int j = 0; j < 4; ++j) {
      int ra = j * 32 + wid * 8 + srow;
      gload16(A + (size_t)(m0 + ra) * K + k0 + schk * 8,
              (char*)&As[b][0] + j * 4096 + (wid << 10));
    }
#pragma unroll
    for (int j = 0; j < 2; ++j) {
      int rb = j * 32 + wid * 8 + srow;
      gload16(Bt + (size_t)(n0 + rb) * K + k0 + schk * 8,
              (char*)&Bs[b][0] + j * 4096 + (wid << 10));
    }
  };

  STAGE(0, 0);
  __syncthreads();
  int cur = 0;
  for (int kt = 0; kt < nkt; ++kt) {
    if (kt + 1 < nkt) STAGE(cur ^ 1, (kt + 1) << 6);
#pragma unroll
    for (int kh = 0; kh < 2; ++kh) {
      s16x8 af[4], bq[2];
#pragma unroll
      for (int i = 0; i < 4; ++i) {
        int rA = wr * 64 + i * 16 + qi;
        af[i] = *(const s16x8*)((const char*)&As[cur][0] + rA * 128 + ((((kh << 2) | g) ^ (rA & 7)) << 4));
      }
#pragma unroll
      for (int jn = 0; jn < 2; ++jn) {
        int rB = wc * 32 + jn * 16 + qi;
        bq[jn] = *(const s16x8*)((const char*)&Bs[cur][0] + rB * 128 + ((((kh << 2) | g) ^ (rB & 7)) << 4));
      }
      __builtin_amdgcn_s_setprio(1);
#pragma unroll
      for (int i = 0; i < 4; ++i)
#pragma unroll
        for (int jn = 0; jn < 2; ++jn)
          acc[i][jn] = __builtin_amdgcn_mfma_f32_16x16x32_bf16(af[i], bq[jn], acc[i][jn], 0, 0, 0);
      __builtin_amdgcn_s_setprio(0);
    }
    __syncthreads();
    cur ^= 1;
  }
#pragma unroll
  for (int i = 0; i < 4; ++i)
#pragma unroll
    for (int jn = 0; jn < 2; ++jn) {
      int row = m0 + wr * 64 + i * 16 + g * 4;
      int col = n0 + wc * 32 + jn * 16 + qi;
#pragma unroll
      for (int r = 0; r < 4; ++r)
        C[(size_t)(row + r) * N + col] = acc[i][jn][r];
    }
}

// Flash attention, causal GQA — R5/R12 best-measured config (78.4us) + VALU trims:
// (1) l computed via ones-MFMA on the underused matrix pipe (lacc = mfma(ones, pf, lacc);
//     every lane's lacc[0] holds l for its q column -> no per-step VALU adds, no shuffles);
// (2) mask+exp fused into one loop. Everything else identical to R12.
__global__ __launch_bounds__(512) void k_attn(const unsigned short* __restrict__ q,
                                              const unsigned short* __restrict__ kk,
                                              const unsigned short* __restrict__ vt,
                                              unsigned short* __restrict__ o) {
  __shared__ __attribute__((aligned(16))) unsigned short Kl[2][64 * 64];
  __shared__ __attribute__((aligned(16))) unsigned short Vl[2][64 * 64];
  __shared__ __attribute__((aligned(16))) unsigned short Pl[8][1536];  // 1024 used + pad -> 56KB total
  const int tid = threadIdx.x;
  const int bid = blockIdx.x;
  const int work = (bid & 7) * 64 + (bid >> 3);    // XCD-chunked: 2 heads per XCD
  const int h = work >> 5;
  const int i0 = work & 31;
  const int hv = h >> 2;
  const int wid = tid >> 6, lane = tid & 63, g = lane >> 4, qi = lane & 15;
  const int qt = (wid < 4) ? i0 : (63 - i0);       // per-wave q-tile
  const int smax = 63 - i0;
  char* pb = (char*)&Pl[wid][0];

  auto STAGE = [&](int b, int s) {
    const int kv0 = s * 64;
    const int r = wid * 8 + (lane >> 3), c8 = (lane & 7) * 8;
    gload16(kk + ((size_t)hv * TT + kv0 + r) * 64 + c8, (char*)&Kl[b][0] + (wid << 10));
    gload16(vt + ((size_t)hv * 64 + r) * TT + kv0 + c8, (char*)&Vl[b][0] + (wid << 10));
  };

  const int qg = qt * 64 + (wid & 3) * 16 + qi;
  s16x8 qf[2];
#pragma unroll
  for (int kh = 0; kh < 2; ++kh)
    qf[kh] = *(const s16x8*)(q + ((size_t)h * TT + qg) * 64 + kh * 32 + g * 8);
  f32x4 acc[4] = {};
  f32x4 lacc = {};
  s16x8 onef;
#pragma unroll
  for (int e = 0; e < 8; ++e) onef[e] = (short)0x3F80;   // bf16 1.0

  STAGE(0, 0);
  __syncthreads();
  int cur = 0;
  for (int s = 0; s <= smax; ++s) {
    if (s < smax) STAGE(cur ^ 1, s + 1);
    if (s <= qt) {
      const int kv0 = s * 64;
      f32x4 sacc[4] = {};
#pragma unroll
      for (int kh = 0; kh < 2; ++kh) {
        s16x8 kf[4];
#pragma unroll
        for (int cf = 0; cf < 4; ++cf) {
          int row = cf * 16 + qi;
          kf[cf] = *(const s16x8*)((const char*)&Kl[cur][0] + row * 128 + ((((kh << 2) | g) ^ (row & 7)) << 4));
        }
        __builtin_amdgcn_s_setprio(1);
#pragma unroll
        for (int cf = 0; cf < 4; ++cf)
          sacc[cf] = __builtin_amdgcn_mfma_f32_16x16x32_bf16(kf[cf], qf[kh], sacc[cf], 0, 0, 0);
        __builtin_amdgcn_s_setprio(0);
      }
      // fused mask + exp (fixed-max: P = exp2(s) directly, scores bounded by RMSNorm)
      float pv[16];
      if (s == qt) {
#pragma unroll
        for (int cf = 0; cf < 4; ++cf)
#pragma unroll
          for (int r = 0; r < 4; ++r) {
            bool m = (kv0 + cf * 16 + g * 4 + r) > qg;
            pv[cf * 4 + r] = m ? 0.0f : exp2f(sacc[cf][r]);
          }
      } else {
#pragma unroll
        for (int cf = 0; cf < 4; ++cf)
#pragma unroll
          for (int r = 0; r < 4; ++r) pv[cf * 4 + r] = exp2f(sacc[cf][r]);
      }
      // P^T stored as [q][kv] (bf16, swizzled by q&7), one b64 write per cf
#pragma unroll
      for (int cf = 0; cf < 4; ++cf) {
        int chunk = cf * 2 + (g >> 1);
        int base = qi * 128 + ((chunk ^ (qi & 7)) << 4) + ((g & 1) << 3);
        uint2 pw;
        pw.x = cvtpk(pv[cf * 4 + 0], pv[cf * 4 + 1]);
        pw.y = cvtpk(pv[cf * 4 + 2], pv[cf * 4 + 3]);
        *(uint2*)(pb + base) = pw;
      }
#pragma unroll
      for (int kh = 0; kh < 2; ++kh) {
        s16x8 pf = *(const s16x8*)(pb + qi * 128 + ((((kh << 2) | g) ^ (qi & 7)) << 4));
        s16x8 vf[4];
#pragma unroll
        for (int cf = 0; cf < 4; ++cf) {
          int row = cf * 16 + qi;
          vf[cf] = *(const s16x8*)((const char*)&Vl[cur][0] + row * 128 + ((((kh << 2) | g) ^ (row & 7)) << 4));
        }
        __builtin_amdgcn_s_setprio(1);
#pragma unroll
        for (int cf = 0; cf < 4; ++cf)
          acc[cf] = __builtin_amdgcn_mfma_f32_16x16x32_bf16(vf[cf], pf, acc[cf], 0, 0, 0);
        lacc = __builtin_amdgcn_mfma_f32_16x16x32_bf16(onef, pf, lacc, 0, 0, 0);  // l row (free pipe)
        __builtin_amdgcn_s_setprio(0);
      }
    }
    __syncthreads();
    cur ^= 1;
  }
  float inv = 1.0f / lacc[0];     // all lanes in column qi hold l[qg]
#pragma unroll
  for (int cf = 0; cf < 4; ++cf) {
    int col = h * 64 + cf * 16 + g * 4;
    int chunk = col >> 3;
    int chs = (chunk & ~7) | ((chunk & 7) ^ (qg & 7));
    char* ob = (char*)o + (size_t)qg * 2048 + (chs << 4) + ((g & 1) << 3);
    *(unsigned int*)ob = cvtpk(acc[cf][0] * inv, acc[cf][1] * inv);
    *(unsigned int*)(ob + 4) = cvtpk(acc[cf][2] * inv, acc[cf][3] * inv);
  }
}

extern "C" void kernel_launch(void* const* d_in, const int* in_sizes, int n_in,
                              void* d_out, int out_size, void* d_ws, size_t ws_size,
                              hipStream_t stream) {
  const float* hs   = (const float*)d_in[0];
  const float* cosb = (const float*)d_in[1];
  const float* sinb = (const float*)d_in[2];
  const float* Wq   = (const float*)d_in[3];
  const float* Wk   = (const float*)d_in[4];
  const float* Wv   = (const float*)d_in[5];
  const float* Wo   = (const float*)d_in[6];
  const float* qw   = (const float*)d_in[7];
  const float* kw   = (const float*)d_in[8];
  char* ws = (char*)d_ws;
  unsigned short* hs_swz = (unsigned short*)(ws + OFF_HS);
  unsigned short* wqkv   = (unsigned short*)(ws + OFF_WQKV);
  unsigned short* wo_t   = (unsigned short*)(ws + OFF_WO);
  unsigned short* qbf    = (unsigned short*)(ws + OFF_Q);
  unsigned short* kbf    = (unsigned short*)(ws + OFF_K);
  unsigned short* vtb    = (unsigned short*)(ws + OFF_VT);
  unsigned short* obf    = (unsigned short*)(ws + OFF_O);

  k_convert_hs<<<2048, 256, 0, stream>>>(hs, hs_swz);
  k_convert_w_all<<<1280, 256, 0, stream>>>(Wq, Wk, Wv, Wo, wqkv, wo_t);
  k_gemm_qkv<<<dim3(24, 32), 256, 0, stream>>>(hs_swz, wqkv, cosb, sinb, qw, kw, qbf, kbf, vtb);
  k_attn<<<512, 512, 0, stream>>>(qbf, kbf, vtb, obf);
  k_gemm<<<dim3(16, 32), 256, 0, stream>>>(obf, wo_t, (float*)d_out, 4096, 1024, 1024);
}

// Round 19
// 131.031 us; speedup vs baseline: 2.1965x; 1.0160x over previous
//
#include <hip/hip_runtime.h>
#include <stdint.h>

#define TT 4096
#define HIDD 1024

typedef __attribute__((ext_vector_type(4))) float f32x4;
typedef __attribute__((ext_vector_type(8))) short s16x8;

static constexpr float kEps = 1e-6f;
static constexpr float kCsc = 0.125f * 1.44269504088896f;  // scale * log2(e), folded into q

// ---- workspace layout (bytes) ----
static constexpr size_t OFF_HS   = 0;          // bf16 hs swz [4096][1024] 8 MB
static constexpr size_t OFF_WQKV = 8388608;    // bf16 WqkvT  [1536][1024] 3 MB
static constexpr size_t OFF_WO   = 11534336;   // bf16 WoT [1024][1024] 2 MB
static constexpr size_t OFF_Q    = 13631488;   // bf16 q [16][4096][64] 8 MB
static constexpr size_t OFF_K    = 22020096;   // bf16 k swz [4][4096][64] 2 MB
static constexpr size_t OFF_O    = 24117248;   // bf16 attn-out swz [4096][1024] 8 MB
static constexpr size_t OFF_VT   = 38797312;   // bf16 vT swz [4][64][4096] 2 MB

__device__ __forceinline__ unsigned int pk_bf16(float a, float b) {
  union { float f; unsigned int u; } x, y;
  x.f = a; y.f = b;
  unsigned int lo = (x.u + 0x7fffu + ((x.u >> 16) & 1u)) >> 16;
  unsigned int hi = (y.u + 0x7fffu + ((y.u >> 16) & 1u)) >> 16;
  return (lo & 0xffffu) | (hi << 16);
}
__device__ __forceinline__ unsigned int cvtpk(float lo, float hi) {
  unsigned int r;
  asm("v_cvt_pk_bf16_f32 %0, %1, %2" : "=v"(r) : "v"(lo), "v"(hi));
  return r;
}
__device__ __forceinline__ void gload16(const void* g, void* l) {
  __builtin_amdgcn_global_load_lds(
      (const __attribute__((address_space(1))) unsigned int*)g,
      (__attribute__((address_space(3))) unsigned int*)l, 16, 0, 0);
}

// hs fp32 [T][1024] -> bf16 swizzled (16B chunk index XORed by row&7 within 64-elem groups)
__global__ void k_convert_hs(const float* __restrict__ hs, unsigned short* __restrict__ out) {
  int idx = blockIdx.x * 256 + threadIdx.x;  // T*128
  int t = idx >> 7, kc = idx & 127;
  const float4* src = (const float4*)(hs + (size_t)t * HIDD + kc * 8);
  float4 a = src[0], b = src[1];
  int kcs = (kc & ~7) | ((kc & 7) ^ (t & 7));
  uint4 w;
  w.x = pk_bf16(a.x, a.y); w.y = pk_bf16(a.z, a.w);
  w.z = pk_bf16(b.x, b.y); w.w = pk_bf16(b.z, b.w);
  *(uint4*)(out + (size_t)t * HIDD + kcs * 8) = w;
}

// All four weight matrices: fp32 [1024][ncols] -> bf16 W^T [ncols][1024] swizzled by n&7
__global__ void k_convert_w_all(const float* __restrict__ Wq, const float* __restrict__ Wk,
                                const float* __restrict__ Wv, const float* __restrict__ Wo,
                                unsigned short* __restrict__ wqkv, unsigned short* __restrict__ wo_t) {
  int b = blockIdx.x, tid = threadIdx.x;
  const float* W; unsigned short* outT; int nshift, idx;
  if (b < 512)      { W = Wq; outT = wqkv;                nshift = 10; idx = b * 256 + tid; }
  else if (b < 640) { W = Wk; outT = wqkv + 1024 * 1024;  nshift = 8;  idx = (b - 512) * 256 + tid; }
  else if (b < 768) { W = Wv; outT = wqkv + 1280 * 1024;  nshift = 8;  idx = (b - 640) * 256 + tid; }
  else              { W = Wo; outT = wo_t;                nshift = 10; idx = (b - 768) * 256 + tid; }
  int ncols = 1 << nshift;
  int kc = idx >> nshift, n = idx & (ncols - 1);
  float v[8];
#pragma unroll
  for (int e = 0; e < 8; ++e) v[e] = W[(size_t)(kc * 8 + e) * ncols + n];
  int kcs = (kc & ~7) | ((kc & 7) ^ (n & 7));
  uint4 w;
  w.x = pk_bf16(v[0], v[1]); w.y = pk_bf16(v[2], v[3]);
  w.z = pk_bf16(v[4], v[5]); w.w = pk_bf16(v[6], v[7]);
  *(uint4*)(outT + (size_t)n * HIDD + kcs * 8) = w;
}

// Fused QKV GEMM + RMSNorm + RoPE + bf16 layout conversion (R12, verified).
__global__ __launch_bounds__(256) void k_gemm_qkv(const unsigned short* __restrict__ A,
                                                  const unsigned short* __restrict__ Bt,
                                                  const float* __restrict__ cosb,
                                                  const float* __restrict__ sinb,
                                                  const float* __restrict__ qw,
                                                  const float* __restrict__ kw,
                                                  unsigned short* __restrict__ qo,
                                                  unsigned short* __restrict__ ko,
                                                  unsigned short* __restrict__ vt) {
  __shared__ __attribute__((aligned(16))) char smem[49152];
  const int K = HIDD;
  const int tid = threadIdx.x;
  const int m0 = blockIdx.y * 128, slot = blockIdx.x, n0 = slot * 64;
  const int wid = tid >> 6, lane = tid & 63;
  const int g = lane >> 4, qi = lane & 15;
  const int wr = wid >> 1, wc = wid & 1;
  const int srow = lane >> 3, schk = lane & 7;
  f32x4 acc[4][2] = {};
  const int nkt = K >> 6;

  auto STAGE = [&](int b, int k0) {
#pragma unroll
    for (int j = 0; j < 4; ++j) {
      int ra = j * 32 + wid * 8 + srow;
      gload16(A + (size_t)(m0 + ra) * K + k0 + schk * 8,
              smem + b * 16384 + j * 4096 + (wid << 10));
    }
#pragma unroll
    for (int j = 0; j < 2; ++j) {
      int rb = j * 32 + wid * 8 + srow;
      gload16(Bt + (size_t)(n0 + rb) * K + k0 + schk * 8,
              smem + 32768 + b * 8192 + j * 4096 + (wid << 10));
    }
  };

  STAGE(0, 0);
  __syncthreads();
  int cur = 0;
  for (int kt = 0; kt < nkt; ++kt) {
    if (kt + 1 < nkt) STAGE(cur ^ 1, (kt + 1) << 6);
#pragma unroll
    for (int kh = 0; kh < 2; ++kh) {
      s16x8 af[4], bq[2];
#pragma unroll
      for (int i = 0; i < 4; ++i) {
        int rA = wr * 64 + i * 16 + qi;
        af[i] = *(const s16x8*)(smem + cur * 16384 + rA * 128 + ((((kh << 2) | g) ^ (rA & 7)) << 4));
      }
#pragma unroll
      for (int jn = 0; jn < 2; ++jn) {
        int rB = wc * 32 + jn * 16 + qi;
        bq[jn] = *(const s16x8*)(smem + 32768 + cur * 8192 + rB * 128 + ((((kh << 2) | g) ^ (rB & 7)) << 4));
      }
      __builtin_amdgcn_s_setprio(1);
#pragma unroll
      for (int i = 0; i < 4; ++i)
#pragma unroll
        for (int jn = 0; jn < 2; ++jn)
          acc[i][jn] = __builtin_amdgcn_mfma_f32_16x16x32_bf16(af[i], bq[jn], acc[i][jn], 0, 0, 0);
      __builtin_amdgcn_s_setprio(0);
    }
    __syncthreads();
    cur ^= 1;
  }

  // ---- epilogue ----
  float* Cs = (float*)smem;                 // [128][66] f32
#pragma unroll
  for (int i = 0; i < 4; ++i)
#pragma unroll
    for (int jn = 0; jn < 2; ++jn) {
      int row = wr * 64 + i * 16 + g * 4;
      int col = wc * 32 + jn * 16 + qi;
#pragma unroll
      for (int r = 0; r < 4; ++r)
        Cs[(row + r) * 66 + col] = acc[i][jn][r];
    }
  __syncthreads();

  if (slot < 20) {
    const int lr = tid >> 1, hf = tid & 1;
    const int t = m0 + lr;
    const float* self_p = Cs + lr * 66 + hf * 32;
    const float* oth_p  = Cs + lr * 66 + (1 - hf) * 32;
    float ss = 0.0f;
#pragma unroll
    for (int e = 0; e < 32; ++e) { float v = self_p[e]; ss += v * v; }
    ss += __shfl_xor(ss, 1);
    const float rms = rsqrtf(ss * (1.0f / 64.0f) + kEps);
    const float* wvec = (slot < 16) ? qw : kw;
    const float outscale = (slot < 16) ? kCsc : 1.0f;
    unsigned int u[16];
#pragma unroll
    for (int ee = 0; ee < 16; ++ee) {
      float o2[2];
#pragma unroll
      for (int p = 0; p < 2; ++p) {
        int e = 2 * ee + p;
        float c = cosb[t * 32 + e];
        float s = sinb[t * 32 + e];
        float self = self_p[e] * rms * wvec[hf * 32 + e];
        float oth  = oth_p[e]  * rms * wvec[(1 - hf) * 32 + e];
        float r = hf ? (oth * s + self * c) : (self * c - oth * s);
        o2[p] = r * outscale;
      }
      u[ee] = cvtpk(o2[0], o2[1]);
    }
    if (slot < 16) {
      unsigned short* base = qo + ((size_t)slot * TT + t) * 64 + hf * 32;
#pragma unroll
      for (int cidx = 0; cidx < 4; ++cidx) {
        uint4 w; w.x = u[cidx * 4]; w.y = u[cidx * 4 + 1]; w.z = u[cidx * 4 + 2]; w.w = u[cidx * 4 + 3];
        *(uint4*)(base + cidx * 8) = w;
      }
    } else {
      const int hv = slot - 16;
      unsigned short* base = ko + ((size_t)hv * TT + t) * 64;
#pragma unroll
      for (int cidx = 0; cidx < 4; ++cidx) {
        int gc = hf * 4 + cidx;
        uint4 w; w.x = u[cidx * 4]; w.y = u[cidx * 4 + 1]; w.z = u[cidx * 4 + 2]; w.w = u[cidx * 4 + 3];
        *(uint4*)(base + (gc ^ (t & 7)) * 8) = w;
      }
    }
  } else {
    const int hv = slot - 20;
#pragma unroll
    for (int tt = 0; tt < 2; ++tt)
#pragma unroll
      for (int jj = 0; jj < 2; ++jj) {
        int idx = jj * 256 + tid;
        int d = idx >> 3, tc = idx & 7;
        uint4 w;
        w.x = cvtpk(Cs[(tt * 64 + tc * 8 + 0) * 66 + d], Cs[(tt * 64 + tc * 8 + 1) * 66 + d]);
        w.y = cvtpk(Cs[(tt * 64 + tc * 8 + 2) * 66 + d], Cs[(tt * 64 + tc * 8 + 3) * 66 + d]);
        w.z = cvtpk(Cs[(tt * 64 + tc * 8 + 4) * 66 + d], Cs[(tt * 64 + tc * 8 + 5) * 66 + d]);
        w.w = cvtpk(Cs[(tt * 64 + tc * 8 + 6) * 66 + d], Cs[(tt * 64 + tc * 8 + 7) * 66 + d]);
        int tcs = tc ^ (d & 7);
        *(uint4*)(vt + ((size_t)hv * 64 + d) * TT + m0 + tt * 64 + tcs * 8) = w;
      }
  }
}

// C[M][N] = A[M][K] * Bt[N][K]^T ; 128x64 tile, BK=64, 4 waves, dbuf LDS (output proj).
__global__ __launch_bounds__(256) void k_gemm(const unsigned short* __restrict__ A,
                                              const unsigned short* __restrict__ Bt,
                                              float* __restrict__ C, int M, int N, int K) {
  __shared__ __attribute__((aligned(16))) unsigned short As[2][128 * 64];
  __shared__ __attribute__((aligned(16))) unsigned short Bs[2][64 * 64];
  const int tid = threadIdx.x;
  const int m0 = blockIdx.y * 128, n0 = blockIdx.x * 64;
  const int wid = tid >> 6, lane = tid & 63;
  const int g = lane >> 4, qi = lane & 15;
  const int wr = wid >> 1, wc = wid & 1;
  const int srow = lane >> 3, schk = lane & 7;
  f32x4 acc[4][2] = {};
  const int nkt = K >> 6;

  auto STAGE = [&](int b, int k0) {
#pragma unroll
    for (int j = 0; j < 4; ++j) {
      int ra = j * 32 + wid * 8 + srow;
      gload16(A + (size_t)(m0 + ra) * K + k0 + schk * 8,
              (char*)&As[b][0] + j * 4096 + (wid << 10));
    }
#pragma unroll
    for (int j = 0; j < 2; ++j) {
      int rb = j * 32 + wid * 8 + srow;
      gload16(Bt + (size_t)(n0 + rb) * K + k0 + schk * 8,
              (char*)&Bs[b][0] + j * 4096 + (wid << 10));
    }
  };

  STAGE(0, 0);
  __syncthreads();
  int cur = 0;
  for (int kt = 0; kt < nkt; ++kt) {
    if (kt + 1 < nkt) STAGE(cur ^ 1, (kt + 1) << 6);
#pragma unroll
    for (int kh = 0; kh < 2; ++kh) {
      s16x8 af[4], bq[2];
#pragma unroll
      for (int i = 0; i < 4; ++i) {
        int rA = wr * 64 + i * 16 + qi;
        af[i] = *(const s16x8*)((const char*)&As[cur][0] + rA * 128 + ((((kh << 2) | g) ^ (rA & 7)) << 4));
      }
#pragma unroll
      for (int jn = 0; jn < 2; ++jn) {
        int rB = wc * 32 + jn * 16 + qi;
        bq[jn] = *(const s16x8*)((const char*)&Bs[cur][0] + rB * 128 + ((((kh << 2) | g) ^ (rB & 7)) << 4));
      }
      __builtin_amdgcn_s_setprio(1);
#pragma unroll
      for (int i = 0; i < 4; ++i)
#pragma unroll
        for (int jn = 0; jn < 2; ++jn)
          acc[i][jn] = __builtin_amdgcn_mfma_f32_16x16x32_bf16(af[i], bq[jn], acc[i][jn], 0, 0, 0);
      __builtin_amdgcn_s_setprio(0);
    }
    __syncthreads();
    cur ^= 1;
  }
#pragma unroll
  for (int i = 0; i < 4; ++i)
#pragma unroll
    for (int jn = 0; jn < 2; ++jn) {
      int row = m0 + wr * 64 + i * 16 + g * 4;
      int col = n0 + wc * 32 + jn * 16 + qi;
#pragma unroll
      for (int r = 0; r < 4; ++r)
        C[(size_t)(row + r) * N + col] = acc[i][jn][r];
    }
}

// Flash attention, causal GQA — the R5/R12 best-measured configuration (78.4us).
// 512 threads = 8 waves: waves 0-3 own q-tile i0, waves 4-7 own q-tile 63-i0; both
// share the same K/V double-buffered staging. FIXED-MAX exp2 softmax (RMSNorm bounds
// |q.k*scale*log2e| <= 11.6 -> P = exp2(s) directly); normalize by l at the end.
// LDS padded to 56KB so exactly 2 blocks/CU -> even packing of 512 uniform blocks.
__global__ __launch_bounds__(512) void k_attn(const unsigned short* __restrict__ q,
                                              const unsigned short* __restrict__ kk,
                                              const unsigned short* __restrict__ vt,
                                              unsigned short* __restrict__ o) {
  __shared__ __attribute__((aligned(16))) unsigned short Kl[2][64 * 64];
  __shared__ __attribute__((aligned(16))) unsigned short Vl[2][64 * 64];
  __shared__ __attribute__((aligned(16))) unsigned short Pl[8][1536];  // 1024 used + pad -> 56KB total
  const int tid = threadIdx.x;
  const int bid = blockIdx.x;
  const int work = (bid & 7) * 64 + (bid >> 3);    // XCD-chunked: 2 heads per XCD
  const int h = work >> 5;
  const int i0 = work & 31;
  const int hv = h >> 2;
  const int wid = tid >> 6, lane = tid & 63, g = lane >> 4, qi = lane & 15;
  const int qt = (wid < 4) ? i0 : (63 - i0);       // per-wave q-tile
  const int smax = 63 - i0;
  char* pb = (char*)&Pl[wid][0];

  auto STAGE = [&](int b, int s) {
    const int kv0 = s * 64;
    const int r = wid * 8 + (lane >> 3), c8 = (lane & 7) * 8;
    gload16(kk + ((size_t)hv * TT + kv0 + r) * 64 + c8, (char*)&Kl[b][0] + (wid << 10));
    gload16(vt + ((size_t)hv * 64 + r) * TT + kv0 + c8, (char*)&Vl[b][0] + (wid << 10));
  };

  const int qg = qt * 64 + (wid & 3) * 16 + qi;
  s16x8 qf[2];
#pragma unroll
  for (int kh = 0; kh < 2; ++kh)
    qf[kh] = *(const s16x8*)(q + ((size_t)h * TT + qg) * 64 + kh * 32 + g * 8);
  f32x4 acc[4] = {};
  float l0 = 0.0f, l1 = 0.0f;

  STAGE(0, 0);
  __syncthreads();
  int cur = 0;
  for (int s = 0; s <= smax; ++s) {
    if (s < smax) STAGE(cur ^ 1, s + 1);
    if (s <= qt) {
      const int kv0 = s * 64;
      f32x4 sacc[4] = {};
#pragma unroll
      for (int kh = 0; kh < 2; ++kh) {
        s16x8 kf[4];
#pragma unroll
        for (int cf = 0; cf < 4; ++cf) {
          int row = cf * 16 + qi;
          kf[cf] = *(const s16x8*)((const char*)&Kl[cur][0] + row * 128 + ((((kh << 2) | g) ^ (row & 7)) << 4));
        }
        __builtin_amdgcn_s_setprio(1);
#pragma unroll
        for (int cf = 0; cf < 4; ++cf)
          sacc[cf] = __builtin_amdgcn_mfma_f32_16x16x32_bf16(kf[cf], qf[kh], sacc[cf], 0, 0, 0);
        __builtin_amdgcn_s_setprio(0);
      }
      float pv[16];
      if (s == qt) {
#pragma unroll
        for (int cf = 0; cf < 4; ++cf)
#pragma unroll
          for (int r = 0; r < 4; ++r) {
            float v = sacc[cf][r];
            if ((kv0 + cf * 16 + g * 4 + r) > qg) v = -1e30f;
            pv[cf * 4 + r] = v;
          }
      } else {
#pragma unroll
        for (int cf = 0; cf < 4; ++cf)
#pragma unroll
          for (int r = 0; r < 4; ++r) pv[cf * 4 + r] = sacc[cf][r];
      }
#pragma unroll
      for (int i = 0; i < 8; ++i) {
        float e0 = exp2f(pv[2 * i]), e1 = exp2f(pv[2 * i + 1]);
        pv[2 * i] = e0; pv[2 * i + 1] = e1;
        l0 += e0; l1 += e1;
      }
#pragma unroll
      for (int cf = 0; cf < 4; ++cf) {
        int chunk = cf * 2 + (g >> 1);
        int base = qi * 128 + ((chunk ^ (qi & 7)) << 4) + ((g & 1) << 3);
        uint2 pw;
        pw.x = cvtpk(pv[cf * 4 + 0], pv[cf * 4 + 1]);
        pw.y = cvtpk(pv[cf * 4 + 2], pv[cf * 4 + 3]);
        *(uint2*)(pb + base) = pw;
      }
#pragma unroll
      for (int kh = 0; kh < 2; ++kh) {
        s16x8 pf = *(const s16x8*)(pb + qi * 128 + ((((kh << 2) | g) ^ (qi & 7)) << 4));
        s16x8 vf[4];
#pragma unroll
        for (int cf = 0; cf < 4; ++cf) {
          int row = cf * 16 + qi;
          vf[cf] = *(const s16x8*)((const char*)&Vl[cur][0] + row * 128 + ((((kh << 2) | g) ^ (row & 7)) << 4));
        }
        __builtin_amdgcn_s_setprio(1);
#pragma unroll
        for (int cf = 0; cf < 4; ++cf)
          acc[cf] = __builtin_amdgcn_mfma_f32_16x16x32_bf16(vf[cf], pf, acc[cf], 0, 0, 0);
        __builtin_amdgcn_s_setprio(0);
      }
    }
    __syncthreads();
    cur ^= 1;
  }
  float l_run = l0 + l1;
  l_run += __shfl_xor(l_run, 16);
  l_run += __shfl_xor(l_run, 32);
  float inv = 1.0f / l_run;
#pragma unroll
  for (int cf = 0; cf < 4; ++cf) {
    int col = h * 64 + cf * 16 + g * 4;
    int chunk = col >> 3;
    int chs = (chunk & ~7) | ((chunk & 7) ^ (qg & 7));
    char* ob = (char*)o + (size_t)qg * 2048 + (chs << 4) + ((g & 1) << 3);
    *(unsigned int*)ob = cvtpk(acc[cf][0] * inv, acc[cf][1] * inv);
    *(unsigned int*)(ob + 4) = cvtpk(acc[cf][2] * inv, acc[cf][3] * inv);
  }
}

extern "C" void kernel_launch(void* const* d_in, const int* in_sizes, int n_in,
                              void* d_out, int out_size, void* d_ws, size_t ws_size,
                              hipStream_t stream) {
  const float* hs   = (const float*)d_in[0];
  const float* cosb = (const float*)d_in[1];
  const float* sinb = (const float*)d_in[2];
  const float* Wq   = (const float*)d_in[3];
  const float* Wk   = (const float*)d_in[4];
  const float* Wv   = (const float*)d_in[5];
  const float* Wo   = (const float*)d_in[6];
  const float* qw   = (const float*)d_in[7];
  const float* kw   = (const float*)d_in[8];
  char* ws = (char*)d_ws;
  unsigned short* hs_swz = (unsigned short*)(ws + OFF_HS);
  unsigned short* wqkv   = (unsigned short*)(ws + OFF_WQKV);
  unsigned short* wo_t   = (unsigned short*)(ws + OFF_WO);
  unsigned short* qbf    = (unsigned short*)(ws + OFF_Q);
  unsigned short* kbf    = (unsigned short*)(ws + OFF_K);
  unsigned short* vtb    = (unsigned short*)(ws + OFF_VT);
  unsigned short* obf    = (unsigned short*)(ws + OFF_O);

  k_convert_hs<<<2048, 256, 0, stream>>>(hs, hs_swz);
  k_convert_w_all<<<1280, 256, 0, stream>>>(Wq, Wk, Wv, Wo, wqkv, wo_t);
  k_gemm_qkv<<<dim3(24, 32), 256, 0, stream>>>(hs_swz, wqkv, cosb, sinb, qw, kw, qbf, kbf, vtb);
  k_attn<<<512, 512, 0, stream>>>(qbf, kbf, vtb, obf);
  k_gemm<<<dim3(16, 32), 256, 0, stream>>>(obf, wo_t, (float*)d_out, 4096, 1024, 1024);
}